// Round 4
// baseline (1338.864 us; speedup 1.0000x reference)
//
#include <hip/hip_runtime.h>
#include <hip/hip_bf16.h>

// ---------------------------------------------------------------------------
// SwinTransformerBlock3D: H=56 W=56 D=28, C=96, NH=3 HD=32, window 7^3 (N=343),
// shift (3,3,3), NW=256 windows, L=87808 tokens, MLP 96->384->96.
// Round 4: *** f32 global I/O *** (reference dtypes are float32 — reading them
// as bf16 was the NaN source in rounds 1-3: low halves of f32 values are
// garbage bf16 incl. NaN patterns). Internals: bf16 LDS tiles, f32 accumulate.
// Threshold is 2%-relative, so bf16 staging rounding is safely inside budget.
// ---------------------------------------------------------------------------

#define L_TOK 87808

typedef unsigned int uint;

__device__ __forceinline__ float bflo(uint u){ union{uint x; float f;} a; a.x = u << 16; return a.f; }
__device__ __forceinline__ float bfhi(uint u){ union{uint x; float f;} a; a.x = u & 0xffff0000u; return a.f; }
__device__ __forceinline__ float bfval(unsigned short w){ union{uint x; float f;} a; a.x = (uint)w << 16; return a.f; }
__device__ __forceinline__ unsigned short f2bfbits(float f){
  union{float f; uint u;} a; a.f = f;
  uint u = a.u;
  u += 0x7fffu + ((u >> 16) & 1u);           // round-to-nearest-even
  return (unsigned short)(u >> 16);
}
__device__ __forceinline__ uint pack2(float a, float b){
  return ((uint)f2bfbits(b) << 16) | (uint)f2bfbits(a);
}
// pack 8 consecutive f32 -> uint4 of 8 bf16
__device__ __forceinline__ uint4 pack8(const float* p){
  uint4 u;
  u.x = pack2(p[0], p[1]); u.y = pack2(p[2], p[3]);
  u.z = pack2(p[4], p[5]); u.w = pack2(p[6], p[7]);
  return u;
}
__device__ __forceinline__ uint4 pack8g(const float* gp){   // from global, via float4
  float t[8];
  *(float4*)&t[0] = *(const float4*)gp;
  *(float4*)&t[4] = *(const float4*)(gp + 4);
  return pack8(t);
}
__device__ __forceinline__ void load32(const __hip_bfloat16* p, float* o){
  const uint4* u = (const uint4*)p;
  #pragma unroll
  for (int i = 0; i < 4; ++i) {
    uint4 t = u[i];
    o[i*8+0]=bflo(t.x); o[i*8+1]=bfhi(t.x);
    o[i*8+2]=bflo(t.y); o[i*8+3]=bfhi(t.y);
    o[i*8+4]=bflo(t.z); o[i*8+5]=bfhi(t.z);
    o[i*8+6]=bflo(t.w); o[i*8+7]=bfhi(t.w);
  }
}

// ---------------------------------------------------------------------------
// K1: fused LN1 + shift + window-partition gather + per-head QKV GEMM.
// Block 192 thr, tile 64 rows x 96 cols (q|k|v 32 each for head h).
// ---------------------------------------------------------------------------
__global__ __launch_bounds__(192)
void k_qkv_ln(const float* __restrict__ x,
              const float* __restrict__ n1g,
              const float* __restrict__ n1b,
              const float* __restrict__ Wg,
              const float* __restrict__ bias, int h,
              __hip_bfloat16* __restrict__ qh,
              __hip_bfloat16* __restrict__ kh,
              __hip_bfloat16* __restrict__ vh)
{
  __shared__ __align__(16) unsigned short As[64][104];
  __shared__ __align__(16) unsigned short Wt[96][104];
  __shared__ uint srcOff[64];
  __shared__ float gLds[96], bLds[96];
  __shared__ float pSum[192], pSq[192];
  __shared__ float mLds[64], sLds[64];

  const int tid = threadIdx.x;
  const int ty = tid / 24, tx = tid % 24;
  const int row0 = blockIdx.x * 64;

  if (tid < 64) {
    const uint row = (uint)(row0 + tid);
    const uint win = row / 343u, n = row % 343u;
    const uint wh = win >> 5, ww = (win >> 2) & 7u, wd = win & 3u;
    const uint ih = n / 49u, rr = n % 49u, iw = rr / 7u, id = rr % 7u;
    uint gh = wh*7u + ih + 3u; if (gh >= 56u) gh -= 56u;
    uint gw = ww*7u + iw + 3u; if (gw >= 56u) gw -= 56u;
    uint gd = wd*7u + id + 3u; if (gd >= 28u) gd -= 28u;
    srcOff[tid] = ((gh*56u + gw)*28u + gd) * 96u;
  }
  if (tid < 96) { gLds[tid] = n1g[tid]; bLds[tid] = n1b[tid]; }
  for (int i = tid; i < 9216; i += 192) {
    const int k = i / 96, nn = i % 96;
    const int wcol = (nn >> 5)*96 + h*32 + (nn & 31);
    Wt[nn][k] = f2bfbits(Wg[(size_t)k*288 + wcol]);
  }
  __syncthreads();

  // stage A (raw x f32 -> bf16, gathered)
  for (int i = tid; i < 768; i += 192) {
    const int r = i / 12, kk = (i % 12) * 8;
    *(uint4*)&As[r][kk] = pack8g(x + srcOff[r] + kk);
  }
  __syncthreads();

  // LN stats: 3 threads per row, 32 channels each
  {
    const int r = tid & 63, seg = tid >> 6;
    float s = 0.0f, sq = 0.0f;
    #pragma unroll
    for (int j = 0; j < 32; ++j) {
      const float v = bfval(As[r][seg*32 + j]);
      s += v; sq += v*v;
    }
    pSum[tid] = s; pSq[tid] = sq;
  }
  __syncthreads();
  if (tid < 64) {
    const float s  = pSum[tid] + pSum[tid+64] + pSum[tid+128];
    const float sq = pSq[tid] + pSq[tid+64] + pSq[tid+128];
    const float mean = s * (1.0f/96.0f);
    mLds[tid] = mean;
    sLds[tid] = rsqrtf(sq*(1.0f/96.0f) - mean*mean + 1e-5f);
  }
  __syncthreads();

  // normalize in place (each thread rewrites only chunks it staged)
  for (int i = tid; i < 768; i += 192) {
    const int r = i / 12, kk = (i % 12) * 8;
    uint4 u = *(uint4*)&As[r][kk];
    const float m = mLds[r], sc = sLds[r];
    float v[8];
    v[0]=bflo(u.x); v[1]=bfhi(u.x); v[2]=bflo(u.y); v[3]=bfhi(u.y);
    v[4]=bflo(u.z); v[5]=bfhi(u.z); v[6]=bflo(u.w); v[7]=bfhi(u.w);
    #pragma unroll
    for (int j = 0; j < 8; ++j) v[j] = (v[j] - m)*sc*gLds[kk+j] + bLds[kk+j];
    *(uint4*)&As[r][kk] = pack8(v);
  }
  __syncthreads();

  float acc[8][4];
  #pragma unroll
  for (int t = 0; t < 8; ++t)
    #pragma unroll
    for (int c = 0; c < 4; ++c) acc[t][c] = 0.0f;

  #pragma unroll 2
  for (int k8 = 0; k8 < 96; k8 += 8) {
    float wf[4][8];
    #pragma unroll
    for (int c = 0; c < 4; ++c) {
      const uint4 u = *(const uint4*)&Wt[tx + 24*c][k8];
      wf[c][0]=bflo(u.x); wf[c][1]=bfhi(u.x); wf[c][2]=bflo(u.y); wf[c][3]=bfhi(u.y);
      wf[c][4]=bflo(u.z); wf[c][5]=bfhi(u.z); wf[c][6]=bflo(u.w); wf[c][7]=bfhi(u.w);
    }
    #pragma unroll
    for (int t = 0; t < 8; ++t) {
      const uint4 u = *(const uint4*)&As[ty*8 + t][k8];
      const float a0=bflo(u.x), a1=bfhi(u.x), a2=bflo(u.y), a3=bfhi(u.y);
      const float a4=bflo(u.z), a5=bfhi(u.z), a6=bflo(u.w), a7=bfhi(u.w);
      #pragma unroll
      for (int c = 0; c < 4; ++c) {
        acc[t][c] += a0*wf[c][0] + a1*wf[c][1] + a2*wf[c][2] + a3*wf[c][3]
                   + a4*wf[c][4] + a5*wf[c][5] + a6*wf[c][6] + a7*wf[c][7];
      }
    }
  }

  const float qscale = 0.17677669529663687f;   // 32^-0.5
  #pragma unroll
  for (int t = 0; t < 8; ++t) {
    const size_t row = (size_t)(row0 + ty*8 + t);
    #pragma unroll
    for (int c = 0; c < 4; ++c) {
      const int col = tx + 24*c;
      const int part = col >> 5, d = col & 31;
      float v = acc[t][c] + bias[part*96 + h*32 + d];
      if (part == 0) v *= qscale;
      __hip_bfloat16* dst = (part == 0) ? qh : ((part == 1) ? kh : vh);
      dst[row*32 + d] = __float2bfloat16(v);
    }
  }
}

// ---------------------------------------------------------------------------
// K2: attention for one head h, one block per window; output -> ob (f32,
// = d_out used as scratch), layout (win*343+n)*96 + h*32 + d.
// ---------------------------------------------------------------------------
__global__ __launch_bounds__(192)
void k_attn_head(const __hip_bfloat16* __restrict__ qg,
                 const __hip_bfloat16* __restrict__ kg,
                 const __hip_bfloat16* __restrict__ vg,
                 const float* __restrict__ rpbg, int hh,
                 float* __restrict__ ob)
{
  __shared__ __align__(16) unsigned short kls[343*32];
  __shared__ __align__(16) unsigned short vls[343*32];
  __shared__ float rp[2197];
  __shared__ short baseT[343];
  __shared__ unsigned char cntT[343];

  const int tid = threadIdx.x;
  const uint win = blockIdx.x;
  const size_t base = (size_t)win * (343*32);

  for (int ch = tid; ch < 1372; ch += 192) {
    const int i = ch * 8;
    *(uint4*)&kls[i] = *(const uint4*)(kg + base + i);
    *(uint4*)&vls[i] = *(const uint4*)(vg + base + i);
  }
  for (int i = tid; i < 2197; i += 192) rp[i] = rpbg[i*3 + hh];
  const uint wh = win >> 5, ww = (win >> 2) & 7u, wd = win & 3u;
  for (int i = tid; i < 343; i += 192) {
    const uint c0 = (uint)i/49u, rr = (uint)i%49u, c1 = rr/7u, c2 = rr%7u;
    baseT[i] = (short)(c0*169u + c1*13u + c2);
    const uint g0 = wh*7u + c0, g1 = ww*7u + c1, g2 = wd*7u + c2;
    const uint rh = (g0 < 49u) ? 0u : ((g0 < 53u) ? 1u : 2u);
    const uint rw = (g1 < 49u) ? 0u : ((g1 < 53u) ? 1u : 2u);
    const uint rd = (g2 < 21u) ? 0u : ((g2 < 25u) ? 1u : 2u);
    cntT[i] = (unsigned char)(rh*9u + rw*3u + rd);
  }
  __syncthreads();

  const int r0 = tid;
  int r1 = tid + 192;
  const bool hasR1 = (r1 < 343);
  if (!hasR1) r1 = 342;             // compute redundantly, skip the store

  float q0[32], q1[32];
  load32(qg + base + (size_t)r0*32, q0);
  load32(qg + base + (size_t)r1*32, q1);
  float o0[32], o1[32];
  #pragma unroll
  for (int d = 0; d < 32; ++d) { o0[d] = 0.0f; o1[d] = 0.0f; }
  float m0 = -1e30f, m1 = -1e30f, l0 = 0.0f, l1 = 0.0f;
  const int bi0 = (int)baseT[r0] + 1098;
  const int bi1 = (int)baseT[r1] + 1098;
  const int cn0 = cntT[r0], cn1 = cntT[r1];

  for (int j = 0; j < 343; ++j) {
    const uint4* kp = (const uint4*)&kls[j*32];
    float s0a = 0.f, s0b = 0.f, s1a = 0.f, s1b = 0.f;
    #pragma unroll
    for (int cc = 0; cc < 4; ++cc) {
      const uint4 u = kp[cc];
      const int d = cc*8;
      const float f0=bflo(u.x), f1=bfhi(u.x), f2=bflo(u.y), f3=bfhi(u.y);
      const float f4=bflo(u.z), f5=bfhi(u.z), f6=bflo(u.w), f7=bfhi(u.w);
      s0a += q0[d+0]*f0 + q0[d+2]*f2 + q0[d+4]*f4 + q0[d+6]*f6;
      s0b += q0[d+1]*f1 + q0[d+3]*f3 + q0[d+5]*f5 + q0[d+7]*f7;
      s1a += q1[d+0]*f0 + q1[d+2]*f2 + q1[d+4]*f4 + q1[d+6]*f6;
      s1b += q1[d+1]*f1 + q1[d+3]*f3 + q1[d+5]*f5 + q1[d+7]*f7;
    }
    const int bj = (int)baseT[j];
    const int cj = (int)cntT[j];
    const float s0 = s0a + s0b + rp[bi0 - bj] + ((cj == cn0) ? 0.0f : -100.0f);
    const float s1 = s1a + s1b + rp[bi1 - bj] + ((cj == cn1) ? 0.0f : -100.0f);
    if (s0 > m0) {
      const float f = __expf(m0 - s0); m0 = s0; l0 *= f;
      #pragma unroll
      for (int d = 0; d < 32; ++d) o0[d] *= f;
    }
    if (s1 > m1) {
      const float f = __expf(m1 - s1); m1 = s1; l1 *= f;
      #pragma unroll
      for (int d = 0; d < 32; ++d) o1[d] *= f;
    }
    const float p0 = __expf(s0 - m0);
    const float p1 = __expf(s1 - m1);
    l0 += p0; l1 += p1;
    const uint4* vp = (const uint4*)&vls[j*32];
    #pragma unroll
    for (int cc = 0; cc < 4; ++cc) {
      const uint4 u = vp[cc];
      const int d = cc*8;
      const float f0=bflo(u.x), f1=bfhi(u.x), f2=bflo(u.y), f3=bfhi(u.y);
      const float f4=bflo(u.z), f5=bfhi(u.z), f6=bflo(u.w), f7=bfhi(u.w);
      o0[d+0]+=p0*f0; o0[d+1]+=p0*f1; o0[d+2]+=p0*f2; o0[d+3]+=p0*f3;
      o0[d+4]+=p0*f4; o0[d+5]+=p0*f5; o0[d+6]+=p0*f6; o0[d+7]+=p0*f7;
      o1[d+0]+=p1*f0; o1[d+1]+=p1*f1; o1[d+2]+=p1*f2; o1[d+3]+=p1*f3;
      o1[d+4]+=p1*f4; o1[d+5]+=p1*f5; o1[d+6]+=p1*f6; o1[d+7]+=p1*f7;
    }
  }

  {
    const float inv0 = 1.0f / l0;
    float* op = ob + ((size_t)win*343 + (uint)r0)*96 + hh*32;
    #pragma unroll
    for (int cc = 0; cc < 4; ++cc) {
      const int d = cc*8;
      *(float4*)(op + d)     = make_float4(o0[d+0]*inv0, o0[d+1]*inv0, o0[d+2]*inv0, o0[d+3]*inv0);
      *(float4*)(op + d + 4) = make_float4(o0[d+4]*inv0, o0[d+5]*inv0, o0[d+6]*inv0, o0[d+7]*inv0);
    }
  }
  if (hasR1) {
    const float inv1 = 1.0f / l1;
    float* op = ob + ((size_t)win*343 + (uint)r1)*96 + hh*32;
    #pragma unroll
    for (int cc = 0; cc < 4; ++cc) {
      const int d = cc*8;
      *(float4*)(op + d)     = make_float4(o1[d+0]*inv1, o1[d+1]*inv1, o1[d+2]*inv1, o1[d+3]*inv1);
      *(float4*)(op + d + 4) = make_float4(o1[d+4]*inv1, o1[d+5]*inv1, o1[d+6]*inv1, o1[d+7]*inv1);
    }
  }
}

// ---------------------------------------------------------------------------
// K3: proj + window reverse + roll(+3) + residual -> xres (bf16, global order).
// A = ob (f32), xin = x (f32).
// ---------------------------------------------------------------------------
__global__ __launch_bounds__(192)
void k_proj(const float* __restrict__ A,
            const float* __restrict__ Wg,
            const float* __restrict__ bias,
            const float* __restrict__ xin,
            __hip_bfloat16* __restrict__ xres)
{
  __shared__ __align__(16) unsigned short As[64][104];
  __shared__ __align__(16) unsigned short Wt[96][104];
  const int tid = threadIdx.x;
  const int ty = tid / 24, tx = tid % 24;
  const int row0 = blockIdx.x * 64;

  for (int i = tid; i < 768; i += 192) {
    const int r = i / 12, kk = (i % 12) * 8;
    *(uint4*)&As[r][kk] = pack8g(A + (size_t)(row0 + r)*96 + kk);
  }
  for (int i = tid; i < 9216; i += 192) {
    const int k = i / 96, nn = i % 96;
    Wt[nn][k] = f2bfbits(Wg[(size_t)k*96 + nn]);
  }
  __syncthreads();

  float acc[8][4];
  #pragma unroll
  for (int t = 0; t < 8; ++t)
    #pragma unroll
    for (int c = 0; c < 4; ++c) acc[t][c] = 0.0f;

  #pragma unroll 2
  for (int k8 = 0; k8 < 96; k8 += 8) {
    float wf[4][8];
    #pragma unroll
    for (int c = 0; c < 4; ++c) {
      const uint4 u = *(const uint4*)&Wt[tx + 24*c][k8];
      wf[c][0]=bflo(u.x); wf[c][1]=bfhi(u.x); wf[c][2]=bflo(u.y); wf[c][3]=bfhi(u.y);
      wf[c][4]=bflo(u.z); wf[c][5]=bfhi(u.z); wf[c][6]=bflo(u.w); wf[c][7]=bfhi(u.w);
    }
    #pragma unroll
    for (int t = 0; t < 8; ++t) {
      const uint4 u = *(const uint4*)&As[ty*8 + t][k8];
      const float a0=bflo(u.x), a1=bfhi(u.x), a2=bflo(u.y), a3=bfhi(u.y);
      const float a4=bflo(u.z), a5=bfhi(u.z), a6=bflo(u.w), a7=bfhi(u.w);
      #pragma unroll
      for (int c = 0; c < 4; ++c) {
        acc[t][c] += a0*wf[c][0] + a1*wf[c][1] + a2*wf[c][2] + a3*wf[c][3]
                   + a4*wf[c][4] + a5*wf[c][5] + a6*wf[c][6] + a7*wf[c][7];
      }
    }
  }

  #pragma unroll
  for (int t = 0; t < 8; ++t) {
    const uint row = (uint)(row0 + ty*8 + t);
    const uint win = row / 343u, n = row % 343u;
    const uint wh = win >> 5, ww = (win >> 2) & 7u, wd = win & 3u;
    const uint ih = n / 49u, rr = n % 49u, iw = rr / 7u, id = rr % 7u;
    uint gh = wh*7u + ih + 3u; if (gh >= 56u) gh -= 56u;
    uint gw = ww*7u + iw + 3u; if (gw >= 56u) gw -= 56u;
    uint gd = wd*7u + id + 3u; if (gd >= 28u) gd -= 28u;
    const size_t gt = (size_t)((gh*56u + gw)*28u + gd) * 96;
    #pragma unroll
    for (int c = 0; c < 4; ++c) {
      const int col = tx + 24*c;
      xres[gt + col] = __float2bfloat16(acc[t][c] + bias[col] + xin[gt + col]);
    }
  }
}

// ---------------------------------------------------------------------------
// K4: fused LN2 + MLP: out = xres + fc2(GELU(fc1(LN2(xres)))). 32-row tile;
// LN2 stats on staged tile, normalized in place; 32x384 GELU intermediate in
// LDS (bf16). Block 192 thr, 4x4 per thread. out is f32.
// ---------------------------------------------------------------------------
__global__ __launch_bounds__(192)
void k_mlp(const __hip_bfloat16* __restrict__ xresb,
           const float* __restrict__ n2g,
           const float* __restrict__ n2b,
           const float* __restrict__ w1,
           const float* __restrict__ b1,
           const float* __restrict__ w2,
           const float* __restrict__ b2,
           float* __restrict__ out)
{
  __shared__ __align__(16) unsigned short As[32][104];
  __shared__ __align__(16) unsigned short Wt[96][104];
  __shared__ __align__(16) unsigned short inter[32][392];   // 384 + 8 pad
  __shared__ float gLds[96], bLds[96];
  __shared__ float pSum[192], pSq[192];
  __shared__ float mLds[32], sLds[32];
  const int tid = threadIdx.x;
  const int ty = tid / 24, tx = tid % 24;
  const int row0 = blockIdx.x * 32;

  if (tid < 96) { gLds[tid] = n2g[tid]; bLds[tid] = n2b[tid]; }
  for (int i = tid; i < 384; i += 192) {
    const int r = i / 12, kk = (i % 12) * 8;
    *(uint4*)&As[r][kk] = *(const uint4*)(xresb + (size_t)(row0 + r)*96 + kk);
  }
  __syncthreads();

  // LN2 stats: 6 threads per row, 16 channels each
  {
    const int r = tid & 31, seg = tid >> 5;   // seg 0..5
    float s = 0.0f, sq = 0.0f;
    #pragma unroll
    for (int j = 0; j < 16; ++j) {
      const float v = bfval(As[r][seg*16 + j]);
      s += v; sq += v*v;
    }
    pSum[tid] = s; pSq[tid] = sq;
  }
  __syncthreads();
  if (tid < 32) {
    float s = 0.0f, sq = 0.0f;
    #pragma unroll
    for (int k = 0; k < 6; ++k) { s += pSum[tid + 32*k]; sq += pSq[tid + 32*k]; }
    const float mean = s * (1.0f/96.0f);
    mLds[tid] = mean;
    sLds[tid] = rsqrtf(sq*(1.0f/96.0f) - mean*mean + 1e-5f);
  }
  __syncthreads();
  for (int i = tid; i < 384; i += 192) {
    const int r = i / 12, kk = (i % 12) * 8;
    uint4 u = *(uint4*)&As[r][kk];
    const float m = mLds[r], sc = sLds[r];
    float v[8];
    v[0]=bflo(u.x); v[1]=bfhi(u.x); v[2]=bflo(u.y); v[3]=bfhi(u.y);
    v[4]=bflo(u.z); v[5]=bfhi(u.z); v[6]=bflo(u.w); v[7]=bfhi(u.w);
    #pragma unroll
    for (int j = 0; j < 8; ++j) v[j] = (v[j] - m)*sc*gLds[kk+j] + bLds[kk+j];
    *(uint4*)&As[r][kk] = pack8(v);
  }
  // (next barrier orders these writes before As reads)

  // ---- fc1 + GELU, 96-col chunks ----
  for (int ny = 0; ny < 4; ++ny) {
    __syncthreads();
    for (int i = tid; i < 9216; i += 192) {
      const int k = i / 96, nn = i % 96;
      Wt[nn][k] = f2bfbits(w1[(size_t)k*384 + ny*96 + nn]);
    }
    __syncthreads();

    float acc[4][4];
    #pragma unroll
    for (int t = 0; t < 4; ++t)
      #pragma unroll
      for (int c = 0; c < 4; ++c) acc[t][c] = 0.0f;

    #pragma unroll 2
    for (int k8 = 0; k8 < 96; k8 += 8) {
      float wf[4][8];
      #pragma unroll
      for (int c = 0; c < 4; ++c) {
        const uint4 u = *(const uint4*)&Wt[tx + 24*c][k8];
        wf[c][0]=bflo(u.x); wf[c][1]=bfhi(u.x); wf[c][2]=bflo(u.y); wf[c][3]=bfhi(u.y);
        wf[c][4]=bflo(u.z); wf[c][5]=bfhi(u.z); wf[c][6]=bflo(u.w); wf[c][7]=bfhi(u.w);
      }
      #pragma unroll
      for (int t = 0; t < 4; ++t) {
        const uint4 u = *(const uint4*)&As[ty*4 + t][k8];
        const float a0=bflo(u.x), a1=bfhi(u.x), a2=bflo(u.y), a3=bfhi(u.y);
        const float a4=bflo(u.z), a5=bfhi(u.z), a6=bflo(u.w), a7=bfhi(u.w);
        #pragma unroll
        for (int c = 0; c < 4; ++c) {
          acc[t][c] += a0*wf[c][0] + a1*wf[c][1] + a2*wf[c][2] + a3*wf[c][3]
                     + a4*wf[c][4] + a5*wf[c][5] + a6*wf[c][6] + a7*wf[c][7];
        }
      }
    }

    #pragma unroll
    for (int t = 0; t < 4; ++t) {
      #pragma unroll
      for (int c = 0; c < 4; ++c) {
        const int col = tx + 24*c;
        float v = acc[t][c] + b1[ny*96 + col];
        v = 0.5f * v * (1.0f + erff(v * 0.70710678118654752f));
        inter[ty*4 + t][ny*96 + col] = f2bfbits(v);
      }
    }
  }

  // ---- fc2 over 4 K-chunks ----
  float acc2[4][4];
  #pragma unroll
  for (int t = 0; t < 4; ++t)
    #pragma unroll
    for (int c = 0; c < 4; ++c) acc2[t][c] = 0.0f;

  for (int kc = 0; kc < 4; ++kc) {
    __syncthreads();
    for (int i = tid; i < 9216; i += 192) {
      const int k = i / 96, nn = i % 96;
      Wt[nn][k] = f2bfbits(w2[(size_t)(kc*96 + k)*96 + nn]);
    }
    __syncthreads();

    #pragma unroll 2
    for (int k8 = 0; k8 < 96; k8 += 8) {
      float wf[4][8];
      #pragma unroll
      for (int c = 0; c < 4; ++c) {
        const uint4 u = *(const uint4*)&Wt[tx + 24*c][k8];
        wf[c][0]=bflo(u.x); wf[c][1]=bfhi(u.x); wf[c][2]=bflo(u.y); wf[c][3]=bfhi(u.y);
        wf[c][4]=bflo(u.z); wf[c][5]=bfhi(u.z); wf[c][6]=bflo(u.w); wf[c][7]=bfhi(u.w);
      }
      #pragma unroll
      for (int t = 0; t < 4; ++t) {
        const uint4 u = *(const uint4*)&inter[ty*4 + t][kc*96 + k8];
        const float a0=bflo(u.x), a1=bfhi(u.x), a2=bflo(u.y), a3=bfhi(u.y);
        const float a4=bflo(u.z), a5=bfhi(u.z), a6=bflo(u.w), a7=bfhi(u.w);
        #pragma unroll
        for (int c = 0; c < 4; ++c) {
          acc2[t][c] += a0*wf[c][0] + a1*wf[c][1] + a2*wf[c][2] + a3*wf[c][3]
                      + a4*wf[c][4] + a5*wf[c][5] + a6*wf[c][6] + a7*wf[c][7];
        }
      }
    }
  }

  #pragma unroll
  for (int t = 0; t < 4; ++t) {
    const size_t row = (size_t)(row0 + ty*4 + t);
    #pragma unroll
    for (int c = 0; c < 4; ++c) {
      const int col = tx + 24*c;
      out[row*96 + col] = acc2[t][c] + b2[col] + bfval(*(const unsigned short*)&xresb[row*96 + col]);
    }
  }
}

// ---------------------------------------------------------------------------
// Workspace usage: 2E bytes = 16,859,136 (E = L*96 elements).
//   phase A (per head): qh [0, L*32), kh [L*32, L*64), vh [L*64, L*96) bf16
//   phase B: xres bf16 [0, E) overlays dead q/k/v
// d_out (f32, L*96 elements) doubles as scratch for attention output.
// ---------------------------------------------------------------------------
extern "C" void kernel_launch(void* const* d_in, const int* in_sizes, int n_in,
                              void* d_out, int out_size, void* d_ws, size_t ws_size,
                              hipStream_t stream)
{
  (void)in_sizes; (void)n_in; (void)out_size; (void)ws_size;
  const float* x    = (const float*)d_in[0];
  const float* n1g  = (const float*)d_in[1];
  const float* n1b  = (const float*)d_in[2];
  const float* qkvw = (const float*)d_in[3];
  const float* qkvb = (const float*)d_in[4];
  const float* rpb  = (const float*)d_in[5];
  const float* pw   = (const float*)d_in[6];
  const float* pb   = (const float*)d_in[7];
  const float* n2g  = (const float*)d_in[8];
  const float* n2b  = (const float*)d_in[9];
  const float* f1w  = (const float*)d_in[10];
  const float* f1b  = (const float*)d_in[11];
  const float* f2w  = (const float*)d_in[12];
  const float* f2b  = (const float*)d_in[13];
  float* out = (float*)d_out;

  __hip_bfloat16* qh   = (__hip_bfloat16*)d_ws;                 // L*32 each
  __hip_bfloat16* kh   = qh + (size_t)L_TOK*32;
  __hip_bfloat16* vh   = qh + (size_t)L_TOK*64;
  __hip_bfloat16* xres = (__hip_bfloat16*)d_ws;                 // overlays q/k/v
  float*          ob   = out;                                   // d_out as scratch

  for (int h = 0; h < 3; ++h) {
    k_qkv_ln<<<L_TOK/64, 192, 0, stream>>>(x, n1g, n1b, qkvw, qkvb, h, qh, kh, vh);
    k_attn_head<<<256, 192, 0, stream>>>(qh, kh, vh, rpb, h, ob);
  }
  k_proj<<<L_TOK/64, 192, 0, stream>>>(ob, pw, pb, x, xres);
  k_mlp<<<L_TOK/32, 192, 0, stream>>>(xres, n2g, n2b, f1w, f1b, f2w, f2b, out);
}

// Round 5
// 868.130 us; speedup vs baseline: 1.5422x; 1.5422x over previous
//
#include <hip/hip_runtime.h>
#include <hip/hip_bf16.h>

// ---------------------------------------------------------------------------
// SwinTransformerBlock3D, f32 I/O (verified round 4). Round 5: MFMA GEMMs.
// mfma_f32_16x16x32_bf16 layouts (m89/m91-verified):
//   A: lane holds A[m=lane&15][k=(lane>>4)*8+j], j=0..7  (short8, ds_read_b128)
//   B: lane holds B[k=(lane>>4)*8+j][n=lane&15]          (read from Wt[n][k])
//   D: lane reg r holds D[row=(lane>>4)*4+r][col=lane&15]
// Attention kernel unchanged (proven). Pipeline/epilogues identical to round 4.
// ---------------------------------------------------------------------------

#define L_TOK 87808

typedef unsigned int uint;
typedef __attribute__((ext_vector_type(8))) short short8;
typedef __attribute__((ext_vector_type(4))) float f32x4;

__device__ __forceinline__ float bflo(uint u){ union{uint x; float f;} a; a.x = u << 16; return a.f; }
__device__ __forceinline__ float bfhi(uint u){ union{uint x; float f;} a; a.x = u & 0xffff0000u; return a.f; }
__device__ __forceinline__ float bfval(unsigned short w){ union{uint x; float f;} a; a.x = (uint)w << 16; return a.f; }
__device__ __forceinline__ unsigned short f2bfbits(float f){
  union{float f; uint u;} a; a.f = f;
  uint u = a.u;
  u += 0x7fffu + ((u >> 16) & 1u);           // round-to-nearest-even
  return (unsigned short)(u >> 16);
}
__device__ __forceinline__ uint pack2(float a, float b){
  return ((uint)f2bfbits(b) << 16) | (uint)f2bfbits(a);
}
__device__ __forceinline__ uint4 pack8(const float* p){
  uint4 u;
  u.x = pack2(p[0], p[1]); u.y = pack2(p[2], p[3]);
  u.z = pack2(p[4], p[5]); u.w = pack2(p[6], p[7]);
  return u;
}
__device__ __forceinline__ uint4 pack8g(const float* gp){
  float t[8];
  *(float4*)&t[0] = *(const float4*)gp;
  *(float4*)&t[4] = *(const float4*)(gp + 4);
  return pack8(t);
}
__device__ __forceinline__ void load32(const __hip_bfloat16* p, float* o){
  const uint4* u = (const uint4*)p;
  #pragma unroll
  for (int i = 0; i < 4; ++i) {
    uint4 t = u[i];
    o[i*8+0]=bflo(t.x); o[i*8+1]=bfhi(t.x);
    o[i*8+2]=bflo(t.y); o[i*8+3]=bfhi(t.y);
    o[i*8+4]=bflo(t.z); o[i*8+5]=bfhi(t.z);
    o[i*8+6]=bflo(t.w); o[i*8+7]=bfhi(t.w);
  }
}

// ---------------------------------------------------------------------------
// K1: fused LN1 + shift + window gather + per-head QKV GEMM (MFMA).
// 256 thr = 4 waves; tile 64 rows x 96 cols; wave w owns m-tile w (16 rows),
// all 6 n-tiles. K=96 = 3 chunks of 32.
// ---------------------------------------------------------------------------
__global__ __launch_bounds__(256)
void k_qkv_ln(const float* __restrict__ x,
              const float* __restrict__ n1g,
              const float* __restrict__ n1b,
              const float* __restrict__ Wg,
              const float* __restrict__ bias, int h,
              __hip_bfloat16* __restrict__ qh,
              __hip_bfloat16* __restrict__ kh,
              __hip_bfloat16* __restrict__ vh)
{
  __shared__ __align__(16) unsigned short As[64][104];
  __shared__ __align__(16) unsigned short Wt[96][104];
  __shared__ uint srcOff[64];
  __shared__ float gLds[96], bLds[96];
  __shared__ float pSum[256], pSq[256];
  __shared__ float mLds[64], sLds[64];

  const int tid = threadIdx.x;
  const int wave = tid >> 6, lane = tid & 63;
  const int row0 = blockIdx.x * 64;

  if (tid < 64) {
    const uint row = (uint)(row0 + tid);
    const uint win = row / 343u, n = row % 343u;
    const uint wh = win >> 5, ww = (win >> 2) & 7u, wd = win & 3u;
    const uint ih = n / 49u, rr = n % 49u, iw = rr / 7u, id = rr % 7u;
    uint gh = wh*7u + ih + 3u; if (gh >= 56u) gh -= 56u;
    uint gw = ww*7u + iw + 3u; if (gw >= 56u) gw -= 56u;
    uint gd = wd*7u + id + 3u; if (gd >= 28u) gd -= 28u;
    srcOff[tid] = ((gh*56u + gw)*28u + gd) * 96u;
  }
  if (tid < 96) { gLds[tid] = n1g[tid]; bLds[tid] = n1b[tid]; }
  // W stage: Wt[n][k] = W[k][wcol(n)], k-fast for conflict-free LDS writes
  for (int i = tid; i < 1152; i += 256) {
    const int k = i % 96, nn8 = (i / 96) * 8;
    const int wb = (nn8 >> 5)*96 + h*32 + (nn8 & 31);
    float t[8];
    *(float4*)&t[0] = *(const float4*)(Wg + (size_t)k*288 + wb);
    *(float4*)&t[4] = *(const float4*)(Wg + (size_t)k*288 + wb + 4);
    #pragma unroll
    for (int j = 0; j < 8; ++j) Wt[nn8 + j][k] = f2bfbits(t[j]);
  }
  __syncthreads();

  // stage A (gathered f32 -> bf16)
  for (int i = tid; i < 768; i += 256) {
    const int r = i / 12, kk = (i % 12) * 8;
    *(uint4*)&As[r][kk] = pack8g(x + srcOff[r] + kk);
  }
  __syncthreads();

  // LN stats: 4 threads/row x 24 channels
  {
    const int r = tid & 63, seg = tid >> 6;
    float s = 0.0f, sq = 0.0f;
    #pragma unroll
    for (int j = 0; j < 24; ++j) {
      const float v = bfval(As[r][seg*24 + j]);
      s += v; sq += v*v;
    }
    pSum[tid] = s; pSq[tid] = sq;
  }
  __syncthreads();
  if (tid < 64) {
    const float s  = pSum[tid] + pSum[tid+64] + pSum[tid+128] + pSum[tid+192];
    const float sq = pSq[tid] + pSq[tid+64] + pSq[tid+128] + pSq[tid+192];
    const float mean = s * (1.0f/96.0f);
    mLds[tid] = mean;
    sLds[tid] = rsqrtf(sq*(1.0f/96.0f) - mean*mean + 1e-5f);
  }
  __syncthreads();
  for (int i = tid; i < 768; i += 256) {
    const int r = i / 12, kk = (i % 12) * 8;
    uint4 u = *(uint4*)&As[r][kk];
    const float m = mLds[r], sc = sLds[r];
    float v[8];
    v[0]=bflo(u.x); v[1]=bfhi(u.x); v[2]=bflo(u.y); v[3]=bfhi(u.y);
    v[4]=bflo(u.z); v[5]=bfhi(u.z); v[6]=bflo(u.w); v[7]=bfhi(u.w);
    #pragma unroll
    for (int j = 0; j < 8; ++j) v[j] = (v[j] - m)*sc*gLds[kk+j] + bLds[kk+j];
    *(uint4*)&As[r][kk] = pack8(v);
  }
  __syncthreads();

  // MFMA: wave -> m-tile, 6 n-tiles, 3 k-chunks
  f32x4 acc[6];
  #pragma unroll
  for (int i = 0; i < 6; ++i) acc[i] = (f32x4){0.f, 0.f, 0.f, 0.f};
  const int ml = lane & 15, q8 = (lane >> 4) * 8;
  #pragma unroll
  for (int kc = 0; kc < 3; ++kc) {
    const short8 a = *(const short8*)&As[wave*16 + ml][kc*32 + q8];
    #pragma unroll
    for (int nt = 0; nt < 6; ++nt) {
      const short8 b = *(const short8*)&Wt[nt*16 + ml][kc*32 + q8];
      acc[nt] = __builtin_amdgcn_mfma_f32_16x16x32_bf16(a, b, acc[nt], 0, 0, 0);
    }
  }

  const float qscale = 0.17677669529663687f;   // 32^-0.5
  #pragma unroll
  for (int r = 0; r < 4; ++r) {
    const size_t row = (size_t)(row0 + wave*16 + (lane >> 4)*4 + r);
    #pragma unroll
    for (int nt = 0; nt < 6; ++nt) {
      const int col = nt*16 + ml;
      const int part = col >> 5, d = col & 31;
      float v = acc[nt][r] + bias[part*96 + h*32 + d];
      if (part == 0) v *= qscale;
      __hip_bfloat16* dst = (part == 0) ? qh : ((part == 1) ? kh : vh);
      dst[row*32 + d] = __float2bfloat16(v);
    }
  }
}

// ---------------------------------------------------------------------------
// K2: attention (unchanged from round 4, proven correct).
// ---------------------------------------------------------------------------
__global__ __launch_bounds__(192)
void k_attn_head(const __hip_bfloat16* __restrict__ qg,
                 const __hip_bfloat16* __restrict__ kg,
                 const __hip_bfloat16* __restrict__ vg,
                 const float* __restrict__ rpbg, int hh,
                 float* __restrict__ ob)
{
  __shared__ __align__(16) unsigned short kls[343*32];
  __shared__ __align__(16) unsigned short vls[343*32];
  __shared__ float rp[2197];
  __shared__ short baseT[343];
  __shared__ unsigned char cntT[343];

  const int tid = threadIdx.x;
  const uint win = blockIdx.x;
  const size_t base = (size_t)win * (343*32);

  for (int ch = tid; ch < 1372; ch += 192) {
    const int i = ch * 8;
    *(uint4*)&kls[i] = *(const uint4*)(kg + base + i);
    *(uint4*)&vls[i] = *(const uint4*)(vg + base + i);
  }
  for (int i = tid; i < 2197; i += 192) rp[i] = rpbg[i*3 + hh];
  const uint wh = win >> 5, ww = (win >> 2) & 7u, wd = win & 3u;
  for (int i = tid; i < 343; i += 192) {
    const uint c0 = (uint)i/49u, rr = (uint)i%49u, c1 = rr/7u, c2 = rr%7u;
    baseT[i] = (short)(c0*169u + c1*13u + c2);
    const uint g0 = wh*7u + c0, g1 = ww*7u + c1, g2 = wd*7u + c2;
    const uint rh = (g0 < 49u) ? 0u : ((g0 < 53u) ? 1u : 2u);
    const uint rw = (g1 < 49u) ? 0u : ((g1 < 53u) ? 1u : 2u);
    const uint rd = (g2 < 21u) ? 0u : ((g2 < 25u) ? 1u : 2u);
    cntT[i] = (unsigned char)(rh*9u + rw*3u + rd);
  }
  __syncthreads();

  const int r0 = tid;
  int r1 = tid + 192;
  const bool hasR1 = (r1 < 343);
  if (!hasR1) r1 = 342;

  float q0[32], q1[32];
  load32(qg + base + (size_t)r0*32, q0);
  load32(qg + base + (size_t)r1*32, q1);
  float o0[32], o1[32];
  #pragma unroll
  for (int d = 0; d < 32; ++d) { o0[d] = 0.0f; o1[d] = 0.0f; }
  float m0 = -1e30f, m1 = -1e30f, l0 = 0.0f, l1 = 0.0f;
  const int bi0 = (int)baseT[r0] + 1098;
  const int bi1 = (int)baseT[r1] + 1098;
  const int cn0 = cntT[r0], cn1 = cntT[r1];

  for (int j = 0; j < 343; ++j) {
    const uint4* kp = (const uint4*)&kls[j*32];
    float s0a = 0.f, s0b = 0.f, s1a = 0.f, s1b = 0.f;
    #pragma unroll
    for (int cc = 0; cc < 4; ++cc) {
      const uint4 u = kp[cc];
      const int d = cc*8;
      const float f0=bflo(u.x), f1=bfhi(u.x), f2=bflo(u.y), f3=bfhi(u.y);
      const float f4=bflo(u.z), f5=bfhi(u.z), f6=bflo(u.w), f7=bfhi(u.w);
      s0a += q0[d+0]*f0 + q0[d+2]*f2 + q0[d+4]*f4 + q0[d+6]*f6;
      s0b += q0[d+1]*f1 + q0[d+3]*f3 + q0[d+5]*f5 + q0[d+7]*f7;
      s1a += q1[d+0]*f0 + q1[d+2]*f2 + q1[d+4]*f4 + q1[d+6]*f6;
      s1b += q1[d+1]*f1 + q1[d+3]*f3 + q1[d+5]*f5 + q1[d+7]*f7;
    }
    const int bj = (int)baseT[j];
    const int cj = (int)cntT[j];
    const float s0 = s0a + s0b + rp[bi0 - bj] + ((cj == cn0) ? 0.0f : -100.0f);
    const float s1 = s1a + s1b + rp[bi1 - bj] + ((cj == cn1) ? 0.0f : -100.0f);
    if (s0 > m0) {
      const float f = __expf(m0 - s0); m0 = s0; l0 *= f;
      #pragma unroll
      for (int d = 0; d < 32; ++d) o0[d] *= f;
    }
    if (s1 > m1) {
      const float f = __expf(m1 - s1); m1 = s1; l1 *= f;
      #pragma unroll
      for (int d = 0; d < 32; ++d) o1[d] *= f;
    }
    const float p0 = __expf(s0 - m0);
    const float p1 = __expf(s1 - m1);
    l0 += p0; l1 += p1;
    const uint4* vp = (const uint4*)&vls[j*32];
    #pragma unroll
    for (int cc = 0; cc < 4; ++cc) {
      const uint4 u = vp[cc];
      const int d = cc*8;
      const float f0=bflo(u.x), f1=bfhi(u.x), f2=bflo(u.y), f3=bfhi(u.y);
      const float f4=bflo(u.z), f5=bfhi(u.z), f6=bflo(u.w), f7=bfhi(u.w);
      o0[d+0]+=p0*f0; o0[d+1]+=p0*f1; o0[d+2]+=p0*f2; o0[d+3]+=p0*f3;
      o0[d+4]+=p0*f4; o0[d+5]+=p0*f5; o0[d+6]+=p0*f6; o0[d+7]+=p0*f7;
      o1[d+0]+=p1*f0; o1[d+1]+=p1*f1; o1[d+2]+=p1*f2; o1[d+3]+=p1*f3;
      o1[d+4]+=p1*f4; o1[d+5]+=p1*f5; o1[d+6]+=p1*f6; o1[d+7]+=p1*f7;
    }
  }

  {
    const float inv0 = 1.0f / l0;
    float* op = ob + ((size_t)win*343 + (uint)r0)*96 + hh*32;
    #pragma unroll
    for (int cc = 0; cc < 4; ++cc) {
      const int d = cc*8;
      *(float4*)(op + d)     = make_float4(o0[d+0]*inv0, o0[d+1]*inv0, o0[d+2]*inv0, o0[d+3]*inv0);
      *(float4*)(op + d + 4) = make_float4(o0[d+4]*inv0, o0[d+5]*inv0, o0[d+6]*inv0, o0[d+7]*inv0);
    }
  }
  if (hasR1) {
    const float inv1 = 1.0f / l1;
    float* op = ob + ((size_t)win*343 + (uint)r1)*96 + hh*32;
    #pragma unroll
    for (int cc = 0; cc < 4; ++cc) {
      const int d = cc*8;
      *(float4*)(op + d)     = make_float4(o1[d+0]*inv1, o1[d+1]*inv1, o1[d+2]*inv1, o1[d+3]*inv1);
      *(float4*)(op + d + 4) = make_float4(o1[d+4]*inv1, o1[d+5]*inv1, o1[d+6]*inv1, o1[d+7]*inv1);
    }
  }
}

// ---------------------------------------------------------------------------
// K3: proj + window reverse + roll(+3) + residual -> xres bf16 (MFMA).
// ---------------------------------------------------------------------------
__global__ __launch_bounds__(256)
void k_proj(const float* __restrict__ A,
            const float* __restrict__ Wg,
            const float* __restrict__ bias,
            const float* __restrict__ xin,
            __hip_bfloat16* __restrict__ xres)
{
  __shared__ __align__(16) unsigned short As[64][104];
  __shared__ __align__(16) unsigned short Wt[96][104];
  const int tid = threadIdx.x;
  const int wave = tid >> 6, lane = tid & 63;
  const int row0 = blockIdx.x * 64;

  for (int i = tid; i < 768; i += 256) {
    const int r = i / 12, kk = (i % 12) * 8;
    *(uint4*)&As[r][kk] = pack8g(A + (size_t)(row0 + r)*96 + kk);
  }
  for (int i = tid; i < 1152; i += 256) {
    const int k = i % 96, nn8 = (i / 96) * 8;
    float t[8];
    *(float4*)&t[0] = *(const float4*)(Wg + (size_t)k*96 + nn8);
    *(float4*)&t[4] = *(const float4*)(Wg + (size_t)k*96 + nn8 + 4);
    #pragma unroll
    for (int j = 0; j < 8; ++j) Wt[nn8 + j][k] = f2bfbits(t[j]);
  }
  __syncthreads();

  f32x4 acc[6];
  #pragma unroll
  for (int i = 0; i < 6; ++i) acc[i] = (f32x4){0.f, 0.f, 0.f, 0.f};
  const int ml = lane & 15, q8 = (lane >> 4) * 8;
  #pragma unroll
  for (int kc = 0; kc < 3; ++kc) {
    const short8 a = *(const short8*)&As[wave*16 + ml][kc*32 + q8];
    #pragma unroll
    for (int nt = 0; nt < 6; ++nt) {
      const short8 b = *(const short8*)&Wt[nt*16 + ml][kc*32 + q8];
      acc[nt] = __builtin_amdgcn_mfma_f32_16x16x32_bf16(a, b, acc[nt], 0, 0, 0);
    }
  }

  #pragma unroll
  for (int r = 0; r < 4; ++r) {
    const uint row = (uint)(row0 + wave*16 + (lane >> 4)*4 + r);
    const uint win = row / 343u, n = row % 343u;
    const uint wh = win >> 5, ww = (win >> 2) & 7u, wd = win & 3u;
    const uint ih = n / 49u, rr = n % 49u, iw = rr / 7u, id = rr % 7u;
    uint gh = wh*7u + ih + 3u; if (gh >= 56u) gh -= 56u;
    uint gw = ww*7u + iw + 3u; if (gw >= 56u) gw -= 56u;
    uint gd = wd*7u + id + 3u; if (gd >= 28u) gd -= 28u;
    const size_t gt = (size_t)((gh*56u + gw)*28u + gd) * 96;
    #pragma unroll
    for (int nt = 0; nt < 6; ++nt) {
      const int col = nt*16 + ml;
      xres[gt + col] = __float2bfloat16(acc[nt][r] + bias[col] + xin[gt + col]);
    }
  }
}

// ---------------------------------------------------------------------------
// K4: fused LN2 + MLP (MFMA): out = xres + fc2(GELU(fc1(LN2(xres)))).
// 256 thr = 4 waves; 32-row tile; wave w owns tiles t=w*3+i: mt=t/6, nt=t%6.
// inter[32][392] holds GELU output (bf16) in [m][k] layout for fc2 A-frags.
// ---------------------------------------------------------------------------
__global__ __launch_bounds__(256)
void k_mlp(const __hip_bfloat16* __restrict__ xresb,
           const float* __restrict__ n2g,
           const float* __restrict__ n2b,
           const float* __restrict__ w1,
           const float* __restrict__ b1,
           const float* __restrict__ w2,
           const float* __restrict__ b2,
           float* __restrict__ out)
{
  __shared__ __align__(16) unsigned short As[32][104];
  __shared__ __align__(16) unsigned short Wt[96][104];
  __shared__ __align__(16) unsigned short inter[32][392];
  __shared__ float gLds[96], bLds[96];
  __shared__ float pSum[256], pSq[256];
  __shared__ float mLds[32], sLds[32];
  const int tid = threadIdx.x;
  const int wave = tid >> 6, lane = tid & 63;
  const int row0 = blockIdx.x * 32;
  const int ml = lane & 15, q8 = (lane >> 4) * 8;
  const int mt = (wave * 3) / 6;              // 0,0,1,1 for waves 0..3
  const int nt0 = (wave * 3) % 6;             // 0,3,0,3

  if (tid < 96) { gLds[tid] = n2g[tid]; bLds[tid] = n2b[tid]; }
  for (int i = tid; i < 384; i += 256) {
    const int r = i / 12, kk = (i % 12) * 8;
    *(uint4*)&As[r][kk] = *(const uint4*)(xresb + (size_t)(row0 + r)*96 + kk);
  }
  __syncthreads();

  // LN2 stats: 8 threads/row x 12 channels
  {
    const int r = tid & 31, seg = tid >> 5;
    float s = 0.0f, sq = 0.0f;
    #pragma unroll
    for (int j = 0; j < 12; ++j) {
      const float v = bfval(As[r][seg*12 + j]);
      s += v; sq += v*v;
    }
    pSum[tid] = s; pSq[tid] = sq;
  }
  __syncthreads();
  if (tid < 32) {
    float s = 0.0f, sq = 0.0f;
    #pragma unroll
    for (int k = 0; k < 8; ++k) { s += pSum[tid + 32*k]; sq += pSq[tid + 32*k]; }
    const float mean = s * (1.0f/96.0f);
    mLds[tid] = mean;
    sLds[tid] = rsqrtf(sq*(1.0f/96.0f) - mean*mean + 1e-5f);
  }
  __syncthreads();
  for (int i = tid; i < 384; i += 256) {
    const int r = i / 12, kk = (i % 12) * 8;
    uint4 u = *(uint4*)&As[r][kk];
    const float m = mLds[r], sc = sLds[r];
    float v[8];
    v[0]=bflo(u.x); v[1]=bfhi(u.x); v[2]=bflo(u.y); v[3]=bfhi(u.y);
    v[4]=bflo(u.z); v[5]=bfhi(u.z); v[6]=bflo(u.w); v[7]=bfhi(u.w);
    #pragma unroll
    for (int j = 0; j < 8; ++j) v[j] = (v[j] - m)*sc*gLds[kk+j] + bLds[kk+j];
    *(uint4*)&As[r][kk] = pack8(v);
  }

  // ---- fc1 + GELU: 4 chunks of 96 cols ----
  for (int ny = 0; ny < 4; ++ny) {
    __syncthreads();
    for (int i = tid; i < 1152; i += 256) {
      const int k = i % 96, nn8 = (i / 96) * 8;
      float t[8];
      *(float4*)&t[0] = *(const float4*)(w1 + (size_t)k*384 + ny*96 + nn8);
      *(float4*)&t[4] = *(const float4*)(w1 + (size_t)k*384 + ny*96 + nn8 + 4);
      #pragma unroll
      for (int j = 0; j < 8; ++j) Wt[nn8 + j][k] = f2bfbits(t[j]);
    }
    __syncthreads();

    f32x4 acc[3];
    #pragma unroll
    for (int i = 0; i < 3; ++i) acc[i] = (f32x4){0.f, 0.f, 0.f, 0.f};
    #pragma unroll
    for (int kc = 0; kc < 3; ++kc) {
      const short8 a = *(const short8*)&As[mt*16 + ml][kc*32 + q8];
      #pragma unroll
      for (int i = 0; i < 3; ++i) {
        const short8 b = *(const short8*)&Wt[(nt0 + i)*16 + ml][kc*32 + q8];
        acc[i] = __builtin_amdgcn_mfma_f32_16x16x32_bf16(a, b, acc[i], 0, 0, 0);
      }
    }
    #pragma unroll
    for (int i = 0; i < 3; ++i) {
      #pragma unroll
      for (int r = 0; r < 4; ++r) {
        const int row = mt*16 + (lane >> 4)*4 + r;
        const int col = ny*96 + (nt0 + i)*16 + ml;
        float v = acc[i][r] + b1[col];
        v = 0.5f * v * (1.0f + erff(v * 0.70710678118654752f));
        inter[row][col] = f2bfbits(v);
      }
    }
  }

  // ---- fc2: K=384 over 4 staged chunks ----
  f32x4 acc2[3];
  #pragma unroll
  for (int i = 0; i < 3; ++i) acc2[i] = (f32x4){0.f, 0.f, 0.f, 0.f};
  for (int kc4 = 0; kc4 < 4; ++kc4) {
    __syncthreads();
    for (int i = tid; i < 1152; i += 256) {
      const int k = i % 96, nn8 = (i / 96) * 8;
      float t[8];
      *(float4*)&t[0] = *(const float4*)(w2 + (size_t)(kc4*96 + k)*96 + nn8);
      *(float4*)&t[4] = *(const float4*)(w2 + (size_t)(kc4*96 + k)*96 + nn8 + 4);
      #pragma unroll
      for (int j = 0; j < 8; ++j) Wt[nn8 + j][k] = f2bfbits(t[j]);
    }
    __syncthreads();

    #pragma unroll
    for (int kc = 0; kc < 3; ++kc) {
      const short8 a = *(const short8*)&inter[mt*16 + ml][kc4*96 + kc*32 + q8];
      #pragma unroll
      for (int i = 0; i < 3; ++i) {
        const short8 b = *(const short8*)&Wt[(nt0 + i)*16 + ml][kc*32 + q8];
        acc2[i] = __builtin_amdgcn_mfma_f32_16x16x32_bf16(a, b, acc2[i], 0, 0, 0);
      }
    }
  }

  const unsigned short* xu = (const unsigned short*)xresb;
  #pragma unroll
  for (int i = 0; i < 3; ++i) {
    #pragma unroll
    for (int r = 0; r < 4; ++r) {
      const size_t row = (size_t)(row0 + mt*16 + (lane >> 4)*4 + r);
      const int col = (nt0 + i)*16 + ml;
      out[row*96 + col] = acc2[i][r] + b2[col] + bfval(xu[row*96 + col]);
    }
  }
}

// ---------------------------------------------------------------------------
// Workspace: 2E bytes (proven). qh/kh/vh per head; xres overlays after attn.
// d_out (f32) doubles as attention-output scratch.
// ---------------------------------------------------------------------------
extern "C" void kernel_launch(void* const* d_in, const int* in_sizes, int n_in,
                              void* d_out, int out_size, void* d_ws, size_t ws_size,
                              hipStream_t stream)
{
  (void)in_sizes; (void)n_in; (void)out_size; (void)ws_size;
  const float* x    = (const float*)d_in[0];
  const float* n1g  = (const float*)d_in[1];
  const float* n1b  = (const float*)d_in[2];
  const float* qkvw = (const float*)d_in[3];
  const float* qkvb = (const float*)d_in[4];
  const float* rpb  = (const float*)d_in[5];
  const float* pw   = (const float*)d_in[6];
  const float* pb   = (const float*)d_in[7];
  const float* n2g  = (const float*)d_in[8];
  const float* n2b  = (const float*)d_in[9];
  const float* f1w  = (const float*)d_in[10];
  const float* f1b  = (const float*)d_in[11];
  const float* f2w  = (const float*)d_in[12];
  const float* f2b  = (const float*)d_in[13];
  float* out = (float*)d_out;

  __hip_bfloat16* qh   = (__hip_bfloat16*)d_ws;
  __hip_bfloat16* kh   = qh + (size_t)L_TOK*32;
  __hip_bfloat16* vh   = qh + (size_t)L_TOK*64;
  __hip_bfloat16* xres = (__hip_bfloat16*)d_ws;
  float*          ob   = out;

  for (int h = 0; h < 3; ++h) {
    k_qkv_ln<<<L_TOK/64, 256, 0, stream>>>(x, n1g, n1b, qkvw, qkvb, h, qh, kh, vh);
    k_attn_head<<<256, 192, 0, stream>>>(qh, kh, vh, rpb, h, ob);
  }
  k_proj<<<L_TOK/64, 256, 0, stream>>>(ob, pw, pb, x, xres);
  k_mlp<<<L_TOK/32, 256, 0, stream>>>(xres, n2g, n2b, f1w, f1b, f2w, f2b, out);
}

// Round 6
// 756.092 us; speedup vs baseline: 1.7708x; 1.1482x over previous
//
#include <hip/hip_runtime.h>
#include <hip/hip_bf16.h>

// ---------------------------------------------------------------------------
// SwinTransformerBlock3D, f32 I/O. Round 6: single-launch all-heads QKV +
// single-launch all-heads attention (grid 768 -> 3 blocks/CU) when ws_size
// permits (>= 50.6 MB); fallback = round-5 per-head loop. Inner loops
// unchanged from round 5 (proven, absmax 0.031).
// ---------------------------------------------------------------------------

#define L_TOK 87808

typedef unsigned int uint;
typedef __attribute__((ext_vector_type(8))) short short8;
typedef __attribute__((ext_vector_type(4))) float f32x4;

__device__ __forceinline__ float bflo(uint u){ union{uint x; float f;} a; a.x = u << 16; return a.f; }
__device__ __forceinline__ float bfhi(uint u){ union{uint x; float f;} a; a.x = u & 0xffff0000u; return a.f; }
__device__ __forceinline__ float bfval(unsigned short w){ union{uint x; float f;} a; a.x = (uint)w << 16; return a.f; }
__device__ __forceinline__ unsigned short f2bfbits(float f){
  union{float f; uint u;} a; a.f = f;
  uint u = a.u;
  u += 0x7fffu + ((u >> 16) & 1u);           // round-to-nearest-even
  return (unsigned short)(u >> 16);
}
__device__ __forceinline__ uint pack2(float a, float b){
  return ((uint)f2bfbits(b) << 16) | (uint)f2bfbits(a);
}
__device__ __forceinline__ uint4 pack8(const float* p){
  uint4 u;
  u.x = pack2(p[0], p[1]); u.y = pack2(p[2], p[3]);
  u.z = pack2(p[4], p[5]); u.w = pack2(p[6], p[7]);
  return u;
}
__device__ __forceinline__ uint4 pack8g(const float* gp){
  float t[8];
  *(float4*)&t[0] = *(const float4*)gp;
  *(float4*)&t[4] = *(const float4*)(gp + 4);
  return pack8(t);
}
__device__ __forceinline__ void load32(const __hip_bfloat16* p, float* o){
  const uint4* u = (const uint4*)p;
  #pragma unroll
  for (int i = 0; i < 4; ++i) {
    uint4 t = u[i];
    o[i*8+0]=bflo(t.x); o[i*8+1]=bfhi(t.x);
    o[i*8+2]=bflo(t.y); o[i*8+3]=bfhi(t.y);
    o[i*8+4]=bflo(t.z); o[i*8+5]=bfhi(t.z);
    o[i*8+6]=bflo(t.w); o[i*8+7]=bfhi(t.w);
  }
}

// ---------------------------------------------------------------------------
// K1: fused LN1 + shift + window gather + per-head QKV GEMM (MFMA).
// head index = blockIdx.y (fused) or hParam (fallback); q/k/v base offset
// = h * headStride (0 in fallback).
// ---------------------------------------------------------------------------
__global__ __launch_bounds__(256)
void k_qkv_ln(const float* __restrict__ x,
              const float* __restrict__ n1g,
              const float* __restrict__ n1b,
              const float* __restrict__ Wg,
              const float* __restrict__ bias, int hParam, size_t headStride,
              __hip_bfloat16* __restrict__ qb,
              __hip_bfloat16* __restrict__ kb,
              __hip_bfloat16* __restrict__ vb)
{
  __shared__ __align__(16) unsigned short As[64][104];
  __shared__ __align__(16) unsigned short Wt[96][104];
  __shared__ uint srcOff[64];
  __shared__ float gLds[96], bLds[96];
  __shared__ float pSum[256], pSq[256];
  __shared__ float mLds[64], sLds[64];

  const int tid = threadIdx.x;
  const int wave = tid >> 6, lane = tid & 63;
  const int row0 = blockIdx.x * 64;
  const int h = (gridDim.y > 1) ? (int)blockIdx.y : hParam;
  __hip_bfloat16* qh = qb + (size_t)h * headStride;
  __hip_bfloat16* kh = kb + (size_t)h * headStride;
  __hip_bfloat16* vh = vb + (size_t)h * headStride;

  if (tid < 64) {
    const uint row = (uint)(row0 + tid);
    const uint win = row / 343u, n = row % 343u;
    const uint wh = win >> 5, ww = (win >> 2) & 7u, wd = win & 3u;
    const uint ih = n / 49u, rr = n % 49u, iw = rr / 7u, id = rr % 7u;
    uint gh = wh*7u + ih + 3u; if (gh >= 56u) gh -= 56u;
    uint gw = ww*7u + iw + 3u; if (gw >= 56u) gw -= 56u;
    uint gd = wd*7u + id + 3u; if (gd >= 28u) gd -= 28u;
    srcOff[tid] = ((gh*56u + gw)*28u + gd) * 96u;
  }
  if (tid < 96) { gLds[tid] = n1g[tid]; bLds[tid] = n1b[tid]; }
  for (int i = tid; i < 1152; i += 256) {
    const int k = i % 96, nn8 = (i / 96) * 8;
    const int wb = (nn8 >> 5)*96 + h*32 + (nn8 & 31);
    float t[8];
    *(float4*)&t[0] = *(const float4*)(Wg + (size_t)k*288 + wb);
    *(float4*)&t[4] = *(const float4*)(Wg + (size_t)k*288 + wb + 4);
    #pragma unroll
    for (int j = 0; j < 8; ++j) Wt[nn8 + j][k] = f2bfbits(t[j]);
  }
  __syncthreads();

  for (int i = tid; i < 768; i += 256) {
    const int r = i / 12, kk = (i % 12) * 8;
    *(uint4*)&As[r][kk] = pack8g(x + srcOff[r] + kk);
  }
  __syncthreads();

  {
    const int r = tid & 63, seg = tid >> 6;
    float s = 0.0f, sq = 0.0f;
    #pragma unroll
    for (int j = 0; j < 24; ++j) {
      const float v = bfval(As[r][seg*24 + j]);
      s += v; sq += v*v;
    }
    pSum[tid] = s; pSq[tid] = sq;
  }
  __syncthreads();
  if (tid < 64) {
    const float s  = pSum[tid] + pSum[tid+64] + pSum[tid+128] + pSum[tid+192];
    const float sq = pSq[tid] + pSq[tid+64] + pSq[tid+128] + pSq[tid+192];
    const float mean = s * (1.0f/96.0f);
    mLds[tid] = mean;
    sLds[tid] = rsqrtf(sq*(1.0f/96.0f) - mean*mean + 1e-5f);
  }
  __syncthreads();
  for (int i = tid; i < 768; i += 256) {
    const int r = i / 12, kk = (i % 12) * 8;
    uint4 u = *(uint4*)&As[r][kk];
    const float m = mLds[r], sc = sLds[r];
    float v[8];
    v[0]=bflo(u.x); v[1]=bfhi(u.x); v[2]=bflo(u.y); v[3]=bfhi(u.y);
    v[4]=bflo(u.z); v[5]=bfhi(u.z); v[6]=bflo(u.w); v[7]=bfhi(u.w);
    #pragma unroll
    for (int j = 0; j < 8; ++j) v[j] = (v[j] - m)*sc*gLds[kk+j] + bLds[kk+j];
    *(uint4*)&As[r][kk] = pack8(v);
  }
  __syncthreads();

  f32x4 acc[6];
  #pragma unroll
  for (int i = 0; i < 6; ++i) acc[i] = (f32x4){0.f, 0.f, 0.f, 0.f};
  const int ml = lane & 15, q8 = (lane >> 4) * 8;
  #pragma unroll
  for (int kc = 0; kc < 3; ++kc) {
    const short8 a = *(const short8*)&As[wave*16 + ml][kc*32 + q8];
    #pragma unroll
    for (int nt = 0; nt < 6; ++nt) {
      const short8 b = *(const short8*)&Wt[nt*16 + ml][kc*32 + q8];
      acc[nt] = __builtin_amdgcn_mfma_f32_16x16x32_bf16(a, b, acc[nt], 0, 0, 0);
    }
  }

  const float qscale = 0.17677669529663687f;   // 32^-0.5
  #pragma unroll
  for (int r = 0; r < 4; ++r) {
    const size_t row = (size_t)(row0 + wave*16 + (lane >> 4)*4 + r);
    #pragma unroll
    for (int nt = 0; nt < 6; ++nt) {
      const int col = nt*16 + ml;
      const int part = col >> 5, d = col & 31;
      float v = acc[nt][r] + bias[part*96 + h*32 + d];
      if (part == 0) v *= qscale;
      __hip_bfloat16* dst = (part == 0) ? qh : ((part == 1) ? kh : vh);
      dst[row*32 + d] = __float2bfloat16(v);
    }
  }
}

// ---------------------------------------------------------------------------
// K2: attention; head = blockIdx.y (fused) or hhParam; q/k/v offset by
// hh*headStride.
// ---------------------------------------------------------------------------
__global__ __launch_bounds__(192)
void k_attn_head(const __hip_bfloat16* __restrict__ qg,
                 const __hip_bfloat16* __restrict__ kg,
                 const __hip_bfloat16* __restrict__ vg,
                 size_t headStride,
                 const float* __restrict__ rpbg, int hhParam,
                 float* __restrict__ ob)
{
  __shared__ __align__(16) unsigned short kls[343*32];
  __shared__ __align__(16) unsigned short vls[343*32];
  __shared__ float rp[2197];
  __shared__ short baseT[343];
  __shared__ unsigned char cntT[343];

  const int tid = threadIdx.x;
  const uint win = blockIdx.x;
  const int hh = (gridDim.y > 1) ? (int)blockIdx.y : hhParam;
  const size_t base = (size_t)hh * headStride + (size_t)win * (343*32);

  for (int ch = tid; ch < 1372; ch += 192) {
    const int i = ch * 8;
    *(uint4*)&kls[i] = *(const uint4*)(kg + base + i);
    *(uint4*)&vls[i] = *(const uint4*)(vg + base + i);
  }
  for (int i = tid; i < 2197; i += 192) rp[i] = rpbg[i*3 + hh];
  const uint wh = win >> 5, ww = (win >> 2) & 7u, wd = win & 3u;
  for (int i = tid; i < 343; i += 192) {
    const uint c0 = (uint)i/49u, rr = (uint)i%49u, c1 = rr/7u, c2 = rr%7u;
    baseT[i] = (short)(c0*169u + c1*13u + c2);
    const uint g0 = wh*7u + c0, g1 = ww*7u + c1, g2 = wd*7u + c2;
    const uint rh = (g0 < 49u) ? 0u : ((g0 < 53u) ? 1u : 2u);
    const uint rw = (g1 < 49u) ? 0u : ((g1 < 53u) ? 1u : 2u);
    const uint rd = (g2 < 21u) ? 0u : ((g2 < 25u) ? 1u : 2u);
    cntT[i] = (unsigned char)(rh*9u + rw*3u + rd);
  }
  __syncthreads();

  const int r0 = tid;
  int r1 = tid + 192;
  const bool hasR1 = (r1 < 343);
  if (!hasR1) r1 = 342;

  float q0[32], q1[32];
  load32(qg + base + (size_t)r0*32, q0);
  load32(qg + base + (size_t)r1*32, q1);
  float o0[32], o1[32];
  #pragma unroll
  for (int d = 0; d < 32; ++d) { o0[d] = 0.0f; o1[d] = 0.0f; }
  float m0 = -1e30f, m1 = -1e30f, l0 = 0.0f, l1 = 0.0f;
  const int bi0 = (int)baseT[r0] + 1098;
  const int bi1 = (int)baseT[r1] + 1098;
  const int cn0 = cntT[r0], cn1 = cntT[r1];

  for (int j = 0; j < 343; ++j) {
    const uint4* kp = (const uint4*)&kls[j*32];
    float s0a = 0.f, s0b = 0.f, s1a = 0.f, s1b = 0.f;
    #pragma unroll
    for (int cc = 0; cc < 4; ++cc) {
      const uint4 u = kp[cc];
      const int d = cc*8;
      const float f0=bflo(u.x), f1=bfhi(u.x), f2=bflo(u.y), f3=bfhi(u.y);
      const float f4=bflo(u.z), f5=bfhi(u.z), f6=bflo(u.w), f7=bfhi(u.w);
      s0a += q0[d+0]*f0 + q0[d+2]*f2 + q0[d+4]*f4 + q0[d+6]*f6;
      s0b += q0[d+1]*f1 + q0[d+3]*f3 + q0[d+5]*f5 + q0[d+7]*f7;
      s1a += q1[d+0]*f0 + q1[d+2]*f2 + q1[d+4]*f4 + q1[d+6]*f6;
      s1b += q1[d+1]*f1 + q1[d+3]*f3 + q1[d+5]*f5 + q1[d+7]*f7;
    }
    const int bj = (int)baseT[j];
    const int cj = (int)cntT[j];
    const float s0 = s0a + s0b + rp[bi0 - bj] + ((cj == cn0) ? 0.0f : -100.0f);
    const float s1 = s1a + s1b + rp[bi1 - bj] + ((cj == cn1) ? 0.0f : -100.0f);
    if (s0 > m0) {
      const float f = __expf(m0 - s0); m0 = s0; l0 *= f;
      #pragma unroll
      for (int d = 0; d < 32; ++d) o0[d] *= f;
    }
    if (s1 > m1) {
      const float f = __expf(m1 - s1); m1 = s1; l1 *= f;
      #pragma unroll
      for (int d = 0; d < 32; ++d) o1[d] *= f;
    }
    const float p0 = __expf(s0 - m0);
    const float p1 = __expf(s1 - m1);
    l0 += p0; l1 += p1;
    const uint4* vp = (const uint4*)&vls[j*32];
    #pragma unroll
    for (int cc = 0; cc < 4; ++cc) {
      const uint4 u = vp[cc];
      const int d = cc*8;
      const float f0=bflo(u.x), f1=bfhi(u.x), f2=bflo(u.y), f3=bfhi(u.y);
      const float f4=bflo(u.z), f5=bfhi(u.z), f6=bflo(u.w), f7=bfhi(u.w);
      o0[d+0]+=p0*f0; o0[d+1]+=p0*f1; o0[d+2]+=p0*f2; o0[d+3]+=p0*f3;
      o0[d+4]+=p0*f4; o0[d+5]+=p0*f5; o0[d+6]+=p0*f6; o0[d+7]+=p0*f7;
      o1[d+0]+=p1*f0; o1[d+1]+=p1*f1; o1[d+2]+=p1*f2; o1[d+3]+=p1*f3;
      o1[d+4]+=p1*f4; o1[d+5]+=p1*f5; o1[d+6]+=p1*f6; o1[d+7]+=p1*f7;
    }
  }

  {
    const float inv0 = 1.0f / l0;
    float* op = ob + ((size_t)win*343 + (uint)r0)*96 + hh*32;
    #pragma unroll
    for (int cc = 0; cc < 4; ++cc) {
      const int d = cc*8;
      *(float4*)(op + d)     = make_float4(o0[d+0]*inv0, o0[d+1]*inv0, o0[d+2]*inv0, o0[d+3]*inv0);
      *(float4*)(op + d + 4) = make_float4(o0[d+4]*inv0, o0[d+5]*inv0, o0[d+6]*inv0, o0[d+7]*inv0);
    }
  }
  if (hasR1) {
    const float inv1 = 1.0f / l1;
    float* op = ob + ((size_t)win*343 + (uint)r1)*96 + hh*32;
    #pragma unroll
    for (int cc = 0; cc < 4; ++cc) {
      const int d = cc*8;
      *(float4*)(op + d)     = make_float4(o1[d+0]*inv1, o1[d+1]*inv1, o1[d+2]*inv1, o1[d+3]*inv1);
      *(float4*)(op + d + 4) = make_float4(o1[d+4]*inv1, o1[d+5]*inv1, o1[d+6]*inv1, o1[d+7]*inv1);
    }
  }
}

// ---------------------------------------------------------------------------
// K3: proj + window reverse + roll(+3) + residual -> xres bf16 (MFMA).
// ---------------------------------------------------------------------------
__global__ __launch_bounds__(256)
void k_proj(const float* __restrict__ A,
            const float* __restrict__ Wg,
            const float* __restrict__ bias,
            const float* __restrict__ xin,
            __hip_bfloat16* __restrict__ xres)
{
  __shared__ __align__(16) unsigned short As[64][104];
  __shared__ __align__(16) unsigned short Wt[96][104];
  const int tid = threadIdx.x;
  const int wave = tid >> 6, lane = tid & 63;
  const int row0 = blockIdx.x * 64;

  for (int i = tid; i < 768; i += 256) {
    const int r = i / 12, kk = (i % 12) * 8;
    *(uint4*)&As[r][kk] = pack8g(A + (size_t)(row0 + r)*96 + kk);
  }
  for (int i = tid; i < 1152; i += 256) {
    const int k = i % 96, nn8 = (i / 96) * 8;
    float t[8];
    *(float4*)&t[0] = *(const float4*)(Wg + (size_t)k*96 + nn8);
    *(float4*)&t[4] = *(const float4*)(Wg + (size_t)k*96 + nn8 + 4);
    #pragma unroll
    for (int j = 0; j < 8; ++j) Wt[nn8 + j][k] = f2bfbits(t[j]);
  }
  __syncthreads();

  f32x4 acc[6];
  #pragma unroll
  for (int i = 0; i < 6; ++i) acc[i] = (f32x4){0.f, 0.f, 0.f, 0.f};
  const int ml = lane & 15, q8 = (lane >> 4) * 8;
  #pragma unroll
  for (int kc = 0; kc < 3; ++kc) {
    const short8 a = *(const short8*)&As[wave*16 + ml][kc*32 + q8];
    #pragma unroll
    for (int nt = 0; nt < 6; ++nt) {
      const short8 b = *(const short8*)&Wt[nt*16 + ml][kc*32 + q8];
      acc[nt] = __builtin_amdgcn_mfma_f32_16x16x32_bf16(a, b, acc[nt], 0, 0, 0);
    }
  }

  #pragma unroll
  for (int r = 0; r < 4; ++r) {
    const uint row = (uint)(row0 + wave*16 + (lane >> 4)*4 + r);
    const uint win = row / 343u, n = row % 343u;
    const uint wh = win >> 5, ww = (win >> 2) & 7u, wd = win & 3u;
    const uint ih = n / 49u, rr = n % 49u, iw = rr / 7u, id = rr % 7u;
    uint gh = wh*7u + ih + 3u; if (gh >= 56u) gh -= 56u;
    uint gw = ww*7u + iw + 3u; if (gw >= 56u) gw -= 56u;
    uint gd = wd*7u + id + 3u; if (gd >= 28u) gd -= 28u;
    const size_t gt = (size_t)((gh*56u + gw)*28u + gd) * 96;
    #pragma unroll
    for (int nt = 0; nt < 6; ++nt) {
      const int col = nt*16 + ml;
      xres[gt + col] = __float2bfloat16(acc[nt][r] + bias[col] + xin[gt + col]);
    }
  }
}

// ---------------------------------------------------------------------------
// K4: fused LN2 + MLP (MFMA).
// ---------------------------------------------------------------------------
__global__ __launch_bounds__(256)
void k_mlp(const __hip_bfloat16* __restrict__ xresb,
           const float* __restrict__ n2g,
           const float* __restrict__ n2b,
           const float* __restrict__ w1,
           const float* __restrict__ b1,
           const float* __restrict__ w2,
           const float* __restrict__ b2,
           float* __restrict__ out)
{
  __shared__ __align__(16) unsigned short As[32][104];
  __shared__ __align__(16) unsigned short Wt[96][104];
  __shared__ __align__(16) unsigned short inter[32][392];
  __shared__ float gLds[96], bLds[96];
  __shared__ float pSum[256], pSq[256];
  __shared__ float mLds[32], sLds[32];
  const int tid = threadIdx.x;
  const int wave = tid >> 6, lane = tid & 63;
  const int row0 = blockIdx.x * 32;
  const int ml = lane & 15, q8 = (lane >> 4) * 8;
  const int mt = (wave * 3) / 6;
  const int nt0 = (wave * 3) % 6;

  if (tid < 96) { gLds[tid] = n2g[tid]; bLds[tid] = n2b[tid]; }
  for (int i = tid; i < 384; i += 256) {
    const int r = i / 12, kk = (i % 12) * 8;
    *(uint4*)&As[r][kk] = *(const uint4*)(xresb + (size_t)(row0 + r)*96 + kk);
  }
  __syncthreads();

  {
    const int r = tid & 31, seg = tid >> 5;
    float s = 0.0f, sq = 0.0f;
    #pragma unroll
    for (int j = 0; j < 12; ++j) {
      const float v = bfval(As[r][seg*12 + j]);
      s += v; sq += v*v;
    }
    pSum[tid] = s; pSq[tid] = sq;
  }
  __syncthreads();
  if (tid < 32) {
    float s = 0.0f, sq = 0.0f;
    #pragma unroll
    for (int k = 0; k < 8; ++k) { s += pSum[tid + 32*k]; sq += pSq[tid + 32*k]; }
    const float mean = s * (1.0f/96.0f);
    mLds[tid] = mean;
    sLds[tid] = rsqrtf(sq*(1.0f/96.0f) - mean*mean + 1e-5f);
  }
  __syncthreads();
  for (int i = tid; i < 384; i += 256) {
    const int r = i / 12, kk = (i % 12) * 8;
    uint4 u = *(uint4*)&As[r][kk];
    const float m = mLds[r], sc = sLds[r];
    float v[8];
    v[0]=bflo(u.x); v[1]=bfhi(u.x); v[2]=bflo(u.y); v[3]=bfhi(u.y);
    v[4]=bflo(u.z); v[5]=bfhi(u.z); v[6]=bflo(u.w); v[7]=bfhi(u.w);
    #pragma unroll
    for (int j = 0; j < 8; ++j) v[j] = (v[j] - m)*sc*gLds[kk+j] + bLds[kk+j];
    *(uint4*)&As[r][kk] = pack8(v);
  }

  for (int ny = 0; ny < 4; ++ny) {
    __syncthreads();
    for (int i = tid; i < 1152; i += 256) {
      const int k = i % 96, nn8 = (i / 96) * 8;
      float t[8];
      *(float4*)&t[0] = *(const float4*)(w1 + (size_t)k*384 + ny*96 + nn8);
      *(float4*)&t[4] = *(const float4*)(w1 + (size_t)k*384 + ny*96 + nn8 + 4);
      #pragma unroll
      for (int j = 0; j < 8; ++j) Wt[nn8 + j][k] = f2bfbits(t[j]);
    }
    __syncthreads();

    f32x4 acc[3];
    #pragma unroll
    for (int i = 0; i < 3; ++i) acc[i] = (f32x4){0.f, 0.f, 0.f, 0.f};
    #pragma unroll
    for (int kc = 0; kc < 3; ++kc) {
      const short8 a = *(const short8*)&As[mt*16 + ml][kc*32 + q8];
      #pragma unroll
      for (int i = 0; i < 3; ++i) {
        const short8 b = *(const short8*)&Wt[(nt0 + i)*16 + ml][kc*32 + q8];
        acc[i] = __builtin_amdgcn_mfma_f32_16x16x32_bf16(a, b, acc[i], 0, 0, 0);
      }
    }
    #pragma unroll
    for (int i = 0; i < 3; ++i) {
      #pragma unroll
      for (int r = 0; r < 4; ++r) {
        const int row = mt*16 + (lane >> 4)*4 + r;
        const int col = ny*96 + (nt0 + i)*16 + ml;
        float v = acc[i][r] + b1[col];
        v = 0.5f * v * (1.0f + erff(v * 0.70710678118654752f));
        inter[row][col] = f2bfbits(v);
      }
    }
  }

  f32x4 acc2[3];
  #pragma unroll
  for (int i = 0; i < 3; ++i) acc2[i] = (f32x4){0.f, 0.f, 0.f, 0.f};
  for (int kc4 = 0; kc4 < 4; ++kc4) {
    __syncthreads();
    for (int i = tid; i < 1152; i += 256) {
      const int k = i % 96, nn8 = (i / 96) * 8;
      float t[8];
      *(float4*)&t[0] = *(const float4*)(w2 + (size_t)(kc4*96 + k)*96 + nn8);
      *(float4*)&t[4] = *(const float4*)(w2 + (size_t)(kc4*96 + k)*96 + nn8 + 4);
      #pragma unroll
      for (int j = 0; j < 8; ++j) Wt[nn8 + j][k] = f2bfbits(t[j]);
    }
    __syncthreads();

    #pragma unroll
    for (int kc = 0; kc < 3; ++kc) {
      const short8 a = *(const short8*)&inter[mt*16 + ml][kc4*96 + kc*32 + q8];
      #pragma unroll
      for (int i = 0; i < 3; ++i) {
        const short8 b = *(const short8*)&Wt[(nt0 + i)*16 + ml][kc*32 + q8];
        acc2[i] = __builtin_amdgcn_mfma_f32_16x16x32_bf16(a, b, acc2[i], 0, 0, 0);
      }
    }
  }

  const unsigned short* xu = (const unsigned short*)xresb;
  #pragma unroll
  for (int i = 0; i < 3; ++i) {
    #pragma unroll
    for (int r = 0; r < 4; ++r) {
      const size_t row = (size_t)(row0 + mt*16 + (lane >> 4)*4 + r);
      const int col = (nt0 + i)*16 + ml;
      out[row*96 + col] = acc2[i][r] + b2[col] + bfval(xu[row*96 + col]);
    }
  }
}

// ---------------------------------------------------------------------------
// Launch. Fused path (ws >= 50.6 MB): q/k/v all heads live at once,
// 1 QKV launch (grid L/64 x 3) + 1 attention launch (grid 256 x 3).
// Fallback: round-5 per-head loop (ws >= 16.9 MB).
// ---------------------------------------------------------------------------
extern "C" void kernel_launch(void* const* d_in, const int* in_sizes, int n_in,
                              void* d_out, int out_size, void* d_ws, size_t ws_size,
                              hipStream_t stream)
{
  (void)in_sizes; (void)n_in; (void)out_size;
  const float* x    = (const float*)d_in[0];
  const float* n1g  = (const float*)d_in[1];
  const float* n1b  = (const float*)d_in[2];
  const float* qkvw = (const float*)d_in[3];
  const float* qkvb = (const float*)d_in[4];
  const float* rpb  = (const float*)d_in[5];
  const float* pw   = (const float*)d_in[6];
  const float* pb   = (const float*)d_in[7];
  const float* n2g  = (const float*)d_in[8];
  const float* n2b  = (const float*)d_in[9];
  const float* f1w  = (const float*)d_in[10];
  const float* f1b  = (const float*)d_in[11];
  const float* f2w  = (const float*)d_in[12];
  const float* f2b  = (const float*)d_in[13];
  float* out = (float*)d_out;

  const size_t E = (size_t)L_TOK * 96;           // elements
  __hip_bfloat16* xres = (__hip_bfloat16*)d_ws;  // phase-B overlay (2E bytes)
  float* ob = out;                               // d_out as attention scratch

  if (ws_size >= 6*E) {                          // 6E bytes = 50.6 MB: fused
    __hip_bfloat16* qb = (__hip_bfloat16*)d_ws;  // E elements (all heads)
    __hip_bfloat16* kb = qb + E;
    __hip_bfloat16* vb = kb + E;
    const size_t hs = (size_t)L_TOK * 32;
    k_qkv_ln<<<dim3(L_TOK/64, 3), 256, 0, stream>>>(
        x, n1g, n1b, qkvw, qkvb, 0, hs, qb, kb, vb);
    k_attn_head<<<dim3(256, 3), 192, 0, stream>>>(qb, kb, vb, hs, rpb, 0, ob);
  } else {                                       // per-head fallback (2E bytes)
    __hip_bfloat16* qh = (__hip_bfloat16*)d_ws;
    __hip_bfloat16* kh = qh + (size_t)L_TOK*32;
    __hip_bfloat16* vh = qh + (size_t)L_TOK*64;
    for (int h = 0; h < 3; ++h) {
      k_qkv_ln<<<dim3(L_TOK/64, 1), 256, 0, stream>>>(
          x, n1g, n1b, qkvw, qkvb, h, 0, qh, kh, vh);
      k_attn_head<<<dim3(256, 1), 192, 0, stream>>>(qh, kh, vh, 0, rpb, h, ob);
    }
  }
  k_proj<<<L_TOK/64, 256, 0, stream>>>(ob, pw, pb, x, xres);
  k_mlp<<<L_TOK/32, 256, 0, stream>>>(xres, n2g, n2b, f1w, f1b, f2w, f2b, out);
}

// Round 7
// 425.260 us; speedup vs baseline: 3.1483x; 1.7780x over previous
//
#include <hip/hip_runtime.h>
#include <hip/hip_bf16.h>

// ---------------------------------------------------------------------------
// SwinTransformerBlock3D, f32 I/O. Round 7: MFMA attention.
// Block = (window, head), 128 thr = 2 waves. Per wave: m-tiles mt = wave,
// wave+2, ... (11 each). QK^T: q A-frag + k B-frag from GLOBAL (L1-hot),
// 22 MFMAs -> full 352-col score row in regs. Two-pass softmax with
// shfl_xor(1,2,4,8) row reductions. P -> per-wave LDS [16][352] bf16
// (masked cols exp to 0). PV: P A-frags + vt[dim][token] B-frags (LDS,
// staged via in-LDS transpose of v). All pads are finite*0. LDS 50.0 KB.
// QKV/proj/MLP kernels unchanged from round 6 (proven, absmax 0.031).
// ---------------------------------------------------------------------------

#define L_TOK 87808

typedef unsigned int uint;
typedef __attribute__((ext_vector_type(8))) short short8;
typedef __attribute__((ext_vector_type(4))) float f32x4;

__device__ __forceinline__ float bflo(uint u){ union{uint x; float f;} a; a.x = u << 16; return a.f; }
__device__ __forceinline__ float bfhi(uint u){ union{uint x; float f;} a; a.x = u & 0xffff0000u; return a.f; }
__device__ __forceinline__ float bfval(unsigned short w){ union{uint x; float f;} a; a.x = (uint)w << 16; return a.f; }
__device__ __forceinline__ unsigned short f2bfbits(float f){
  union{float f; uint u;} a; a.f = f;
  uint u = a.u;
  u += 0x7fffu + ((u >> 16) & 1u);           // round-to-nearest-even
  return (unsigned short)(u >> 16);
}
__device__ __forceinline__ uint pack2(float a, float b){
  return ((uint)f2bfbits(b) << 16) | (uint)f2bfbits(a);
}
__device__ __forceinline__ uint4 pack8(const float* p){
  uint4 u;
  u.x = pack2(p[0], p[1]); u.y = pack2(p[2], p[3]);
  u.z = pack2(p[4], p[5]); u.w = pack2(p[6], p[7]);
  return u;
}
__device__ __forceinline__ uint4 pack8g(const float* gp){
  float t[8];
  *(float4*)&t[0] = *(const float4*)gp;
  *(float4*)&t[4] = *(const float4*)(gp + 4);
  return pack8(t);
}

// ---------------------------------------------------------------------------
// K1: fused LN1 + shift + window gather + per-head QKV GEMM (MFMA).
// ---------------------------------------------------------------------------
__global__ __launch_bounds__(256)
void k_qkv_ln(const float* __restrict__ x,
              const float* __restrict__ n1g,
              const float* __restrict__ n1b,
              const float* __restrict__ Wg,
              const float* __restrict__ bias, size_t headStride,
              __hip_bfloat16* __restrict__ qb,
              __hip_bfloat16* __restrict__ kb,
              __hip_bfloat16* __restrict__ vb)
{
  __shared__ __align__(16) unsigned short As[64][104];
  __shared__ __align__(16) unsigned short Wt[96][104];
  __shared__ uint srcOff[64];
  __shared__ float gLds[96], bLds[96];
  __shared__ float pSum[256], pSq[256];
  __shared__ float mLds[64], sLds[64];

  const int tid = threadIdx.x;
  const int wave = tid >> 6, lane = tid & 63;
  const int row0 = blockIdx.x * 64;
  const int h = (int)blockIdx.y;
  __hip_bfloat16* qh = qb + (size_t)h * headStride;
  __hip_bfloat16* kh = kb + (size_t)h * headStride;
  __hip_bfloat16* vh = vb + (size_t)h * headStride;

  if (tid < 64) {
    const uint row = (uint)(row0 + tid);
    const uint win = row / 343u, n = row % 343u;
    const uint wh = win >> 5, ww = (win >> 2) & 7u, wd = win & 3u;
    const uint ih = n / 49u, rr = n % 49u, iw = rr / 7u, id = rr % 7u;
    uint gh = wh*7u + ih + 3u; if (gh >= 56u) gh -= 56u;
    uint gw = ww*7u + iw + 3u; if (gw >= 56u) gw -= 56u;
    uint gd = wd*7u + id + 3u; if (gd >= 28u) gd -= 28u;
    srcOff[tid] = ((gh*56u + gw)*28u + gd) * 96u;
  }
  if (tid < 96) { gLds[tid] = n1g[tid]; bLds[tid] = n1b[tid]; }
  for (int i = tid; i < 1152; i += 256) {
    const int k = i % 96, nn8 = (i / 96) * 8;
    const int wb = (nn8 >> 5)*96 + h*32 + (nn8 & 31);
    float t[8];
    *(float4*)&t[0] = *(const float4*)(Wg + (size_t)k*288 + wb);
    *(float4*)&t[4] = *(const float4*)(Wg + (size_t)k*288 + wb + 4);
    #pragma unroll
    for (int j = 0; j < 8; ++j) Wt[nn8 + j][k] = f2bfbits(t[j]);
  }
  __syncthreads();

  for (int i = tid; i < 768; i += 256) {
    const int r = i / 12, kk = (i % 12) * 8;
    *(uint4*)&As[r][kk] = pack8g(x + srcOff[r] + kk);
  }
  __syncthreads();

  {
    const int r = tid & 63, seg = tid >> 6;
    float s = 0.0f, sq = 0.0f;
    #pragma unroll
    for (int j = 0; j < 24; ++j) {
      const float v = bfval(As[r][seg*24 + j]);
      s += v; sq += v*v;
    }
    pSum[tid] = s; pSq[tid] = sq;
  }
  __syncthreads();
  if (tid < 64) {
    const float s  = pSum[tid] + pSum[tid+64] + pSum[tid+128] + pSum[tid+192];
    const float sq = pSq[tid] + pSq[tid+64] + pSq[tid+128] + pSq[tid+192];
    const float mean = s * (1.0f/96.0f);
    mLds[tid] = mean;
    sLds[tid] = rsqrtf(sq*(1.0f/96.0f) - mean*mean + 1e-5f);
  }
  __syncthreads();
  for (int i = tid; i < 768; i += 256) {
    const int r = i / 12, kk = (i % 12) * 8;
    uint4 u = *(uint4*)&As[r][kk];
    const float m = mLds[r], sc = sLds[r];
    float v[8];
    v[0]=bflo(u.x); v[1]=bfhi(u.x); v[2]=bflo(u.y); v[3]=bfhi(u.y);
    v[4]=bflo(u.z); v[5]=bfhi(u.z); v[6]=bflo(u.w); v[7]=bfhi(u.w);
    #pragma unroll
    for (int j = 0; j < 8; ++j) v[j] = (v[j] - m)*sc*gLds[kk+j] + bLds[kk+j];
    *(uint4*)&As[r][kk] = pack8(v);
  }
  __syncthreads();

  f32x4 acc[6];
  #pragma unroll
  for (int i = 0; i < 6; ++i) acc[i] = (f32x4){0.f, 0.f, 0.f, 0.f};
  const int ml = lane & 15, q8 = (lane >> 4) * 8;
  #pragma unroll
  for (int kc = 0; kc < 3; ++kc) {
    const short8 a = *(const short8*)&As[wave*16 + ml][kc*32 + q8];
    #pragma unroll
    for (int nt = 0; nt < 6; ++nt) {
      const short8 b = *(const short8*)&Wt[nt*16 + ml][kc*32 + q8];
      acc[nt] = __builtin_amdgcn_mfma_f32_16x16x32_bf16(a, b, acc[nt], 0, 0, 0);
    }
  }

  const float qscale = 0.17677669529663687f;   // 32^-0.5
  #pragma unroll
  for (int r = 0; r < 4; ++r) {
    const size_t row = (size_t)(row0 + wave*16 + (lane >> 4)*4 + r);
    #pragma unroll
    for (int nt = 0; nt < 6; ++nt) {
      const int col = nt*16 + ml;
      const int part = col >> 5, d = col & 31;
      float v = acc[nt][r] + bias[part*96 + h*32 + d];
      if (part == 0) v *= qscale;
      __hip_bfloat16* dst = (part == 0) ? qh : ((part == 1) ? kh : vh);
      dst[row*32 + d] = __float2bfloat16(v);
    }
  }
}

// ---------------------------------------------------------------------------
// K2: MFMA attention. Grid (256, 3), block 128 (2 waves).
// ---------------------------------------------------------------------------
__global__ __launch_bounds__(128)
void k_attn_mfma(const __hip_bfloat16* __restrict__ qg,
                 const __hip_bfloat16* __restrict__ kg,
                 const __hip_bfloat16* __restrict__ vg,
                 size_t headStride,
                 const float* __restrict__ rpbg,
                 float* __restrict__ ob)
{
  __shared__ __align__(16) unsigned short vt[32*344 + 16]; // [dim][token], stride 344, +16 zero tail
  __shared__ __align__(16) unsigned short Pbuf[2][16*352]; // per-wave P tile [m][k]
  __shared__ unsigned short rpB[2197];                     // rel-pos bias, bf16
  __shared__ short baseT[352];
  __shared__ unsigned char cntT[352];

  const int tid = threadIdx.x;
  const int wave = tid >> 6, lane = tid & 63;
  const uint win = blockIdx.x;
  const int hh = (int)blockIdx.y;
  const size_t wbase = (size_t)hh * headStride + (size_t)win * (343*32);
  const unsigned short* qw = (const unsigned short*)qg + wbase;
  const unsigned short* kw = (const unsigned short*)kg + wbase;
  const unsigned short* vw = (const unsigned short*)vg + wbase;

  for (int i = tid; i < 2197; i += 128) rpB[i] = f2bfbits(rpbg[i*3 + hh]);
  const uint wh = win >> 5, ww = (win >> 2) & 7u, wd = win & 3u;
  for (int i = tid; i < 352; i += 128) {
    if (i < 343) {
      const uint c0 = (uint)i/49u, rr = (uint)i%49u, c1 = rr/7u, c2 = rr%7u;
      baseT[i] = (short)(c0*169u + c1*13u + c2);
      const uint g0 = wh*7u + c0, g1 = ww*7u + c1, g2 = wd*7u + c2;
      const uint rh = (g0 < 49u) ? 0u : ((g0 < 53u) ? 1u : 2u);
      const uint rw = (g1 < 49u) ? 0u : ((g1 < 53u) ? 1u : 2u);
      const uint rd = (g2 < 21u) ? 0u : ((g2 < 25u) ? 1u : 2u);
      cntT[i] = (unsigned char)(rh*9u + rw*3u + rd);
    } else { baseT[i] = 0; cntT[i] = 255; }
  }
  // stage V transposed: vt[d][t] = v[t][d]
  for (int t = tid; t < 343; t += 128) {
    const uint4* src = (const uint4*)(vw + (size_t)t*32);
    #pragma unroll
    for (int c4 = 0; c4 < 4; ++c4) {
      const uint4 u = src[c4];
      const int d = c4*8;
      vt[(d+0)*344 + t] = (unsigned short)(u.x & 0xffffu);
      vt[(d+1)*344 + t] = (unsigned short)(u.x >> 16);
      vt[(d+2)*344 + t] = (unsigned short)(u.y & 0xffffu);
      vt[(d+3)*344 + t] = (unsigned short)(u.y >> 16);
      vt[(d+4)*344 + t] = (unsigned short)(u.z & 0xffffu);
      vt[(d+5)*344 + t] = (unsigned short)(u.z >> 16);
      vt[(d+6)*344 + t] = (unsigned short)(u.w & 0xffffu);
      vt[(d+7)*344 + t] = (unsigned short)(u.w >> 16);
    }
  }
  if (tid < 32) vt[tid*344 + 343] = 0;   // per-row pad col
  if (tid < 16) vt[32*344 + tid] = 0;    // tail pad (last row's k-overrun)
  __syncthreads();

  const int ml = lane & 15, g8 = (lane >> 4) * 8;
  unsigned short* Pw = &Pbuf[wave][0];

  for (int mt = wave; mt < 22; mt += 2) {
    // QK^T: 22 n-tiles, K=32 in one MFMA each. Rows/cols >=343 masked below.
    const short8 qf = *(const short8*)(qw + (size_t)(mt*16 + ml)*32 + g8);
    f32x4 s[22];
    #pragma unroll
    for (int nt = 0; nt < 22; ++nt) {
      const short8 kf = *(const short8*)(kw + (size_t)(nt*16 + ml)*32 + g8);
      s[nt] = __builtin_amdgcn_mfma_f32_16x16x32_bf16(qf, kf, (f32x4){0.f,0.f,0.f,0.f}, 0, 0, 0);
    }

    int biR[4], cnR[4];
    #pragma unroll
    for (int r = 0; r < 4; ++r) {
      const int gi = mt*16 + (lane >> 4)*4 + r;       // <= 351, in pad range
      biR[r] = (int)baseT[gi] + 1098;
      cnR[r] = (int)cntT[gi];
    }

    float mx[4] = {-1e30f, -1e30f, -1e30f, -1e30f};
    #pragma unroll
    for (int nt = 0; nt < 22; ++nt) {
      const int col = nt*16 + ml;
      const int bj = (int)baseT[col];
      const int cj = (int)cntT[col];
      #pragma unroll
      for (int r = 0; r < 4; ++r) {
        float v = s[nt][r] + bfval(rpB[biR[r] - bj]);
        v += (cj == cnR[r]) ? 0.0f : -100.0f;
        v = (col < 343) ? v : -1e30f;
        s[nt][r] = v;
        mx[r] = fmaxf(mx[r], v);
      }
    }
    float sm[4];
    #pragma unroll
    for (int r = 0; r < 4; ++r) {
      float m = mx[r];
      m = fmaxf(m, __shfl_xor(m, 1));
      m = fmaxf(m, __shfl_xor(m, 2));
      m = fmaxf(m, __shfl_xor(m, 4));
      m = fmaxf(m, __shfl_xor(m, 8));
      mx[r] = m; sm[r] = 0.0f;
    }
    #pragma unroll
    for (int nt = 0; nt < 22; ++nt) {
      #pragma unroll
      for (int r = 0; r < 4; ++r) {
        const float p = __expf(s[nt][r] - mx[r]);   // masked cols -> 0
        s[nt][r] = p;
        sm[r] += p;
      }
    }
    #pragma unroll
    for (int r = 0; r < 4; ++r) {
      float t = sm[r];
      t += __shfl_xor(t, 1);
      t += __shfl_xor(t, 2);
      t += __shfl_xor(t, 4);
      t += __shfl_xor(t, 8);
      sm[r] = t;
    }
    // P -> LDS in A-operand layout [m][k]
    #pragma unroll
    for (int nt = 0; nt < 22; ++nt) {
      #pragma unroll
      for (int r = 0; r < 4; ++r)
        Pw[((lane >> 4)*4 + r)*352 + nt*16 + ml] = f2bfbits(s[nt][r]);
    }
    // PV: 11 k-chunks of 32 tokens, 2 dim-tiles
    f32x4 o0 = {0.f,0.f,0.f,0.f}, o1 = {0.f,0.f,0.f,0.f};
    #pragma unroll
    for (int kc = 0; kc < 11; ++kc) {
      const short8 pf = *(const short8*)&Pw[ml*352 + kc*32 + g8];
      const short8 b0 = *(const short8*)&vt[(size_t)ml*344 + kc*32 + g8];
      const short8 b1 = *(const short8*)&vt[(size_t)(16 + ml)*344 + kc*32 + g8];
      o0 = __builtin_amdgcn_mfma_f32_16x16x32_bf16(pf, b0, o0, 0, 0, 0);
      o1 = __builtin_amdgcn_mfma_f32_16x16x32_bf16(pf, b1, o1, 0, 0, 0);
    }
    #pragma unroll
    for (int r = 0; r < 4; ++r) {
      const int row = mt*16 + (lane >> 4)*4 + r;
      if (row < 343) {
        const float inv = 1.0f / sm[r];
        float* op = ob + ((size_t)win*343 + (uint)row)*96 + hh*32;
        op[ml]      = o0[r] * inv;
        op[16 + ml] = o1[r] * inv;
      }
    }
  }
}

// ---------------------------------------------------------------------------
// K3: proj + window reverse + roll(+3) + residual -> xres bf16 (MFMA).
// ---------------------------------------------------------------------------
__global__ __launch_bounds__(256)
void k_proj(const float* __restrict__ A,
            const float* __restrict__ Wg,
            const float* __restrict__ bias,
            const float* __restrict__ xin,
            __hip_bfloat16* __restrict__ xres)
{
  __shared__ __align__(16) unsigned short As[64][104];
  __shared__ __align__(16) unsigned short Wt[96][104];
  const int tid = threadIdx.x;
  const int wave = tid >> 6, lane = tid & 63;
  const int row0 = blockIdx.x * 64;

  for (int i = tid; i < 768; i += 256) {
    const int r = i / 12, kk = (i % 12) * 8;
    *(uint4*)&As[r][kk] = pack8g(A + (size_t)(row0 + r)*96 + kk);
  }
  for (int i = tid; i < 1152; i += 256) {
    const int k = i % 96, nn8 = (i / 96) * 8;
    float t[8];
    *(float4*)&t[0] = *(const float4*)(Wg + (size_t)k*96 + nn8);
    *(float4*)&t[4] = *(const float4*)(Wg + (size_t)k*96 + nn8 + 4);
    #pragma unroll
    for (int j = 0; j < 8; ++j) Wt[nn8 + j][k] = f2bfbits(t[j]);
  }
  __syncthreads();

  f32x4 acc[6];
  #pragma unroll
  for (int i = 0; i < 6; ++i) acc[i] = (f32x4){0.f, 0.f, 0.f, 0.f};
  const int ml = lane & 15, q8 = (lane >> 4) * 8;
  #pragma unroll
  for (int kc = 0; kc < 3; ++kc) {
    const short8 a = *(const short8*)&As[wave*16 + ml][kc*32 + q8];
    #pragma unroll
    for (int nt = 0; nt < 6; ++nt) {
      const short8 b = *(const short8*)&Wt[nt*16 + ml][kc*32 + q8];
      acc[nt] = __builtin_amdgcn_mfma_f32_16x16x32_bf16(a, b, acc[nt], 0, 0, 0);
    }
  }

  #pragma unroll
  for (int r = 0; r < 4; ++r) {
    const uint row = (uint)(row0 + wave*16 + (lane >> 4)*4 + r);
    const uint win = row / 343u, n = row % 343u;
    const uint wh = win >> 5, ww = (win >> 2) & 7u, wd = win & 3u;
    const uint ih = n / 49u, rr = n % 49u, iw = rr / 7u, id = rr % 7u;
    uint gh = wh*7u + ih + 3u; if (gh >= 56u) gh -= 56u;
    uint gw = ww*7u + iw + 3u; if (gw >= 56u) gw -= 56u;
    uint gd = wd*7u + id + 3u; if (gd >= 28u) gd -= 28u;
    const size_t gt = (size_t)((gh*56u + gw)*28u + gd) * 96;
    #pragma unroll
    for (int nt = 0; nt < 6; ++nt) {
      const int col = nt*16 + ml;
      xres[gt + col] = __float2bfloat16(acc[nt][r] + bias[col] + xin[gt + col]);
    }
  }
}

// ---------------------------------------------------------------------------
// K4: fused LN2 + MLP (MFMA).
// ---------------------------------------------------------------------------
__global__ __launch_bounds__(256)
void k_mlp(const __hip_bfloat16* __restrict__ xresb,
           const float* __restrict__ n2g,
           const float* __restrict__ n2b,
           const float* __restrict__ w1,
           const float* __restrict__ b1,
           const float* __restrict__ w2,
           const float* __restrict__ b2,
           float* __restrict__ out)
{
  __shared__ __align__(16) unsigned short As[32][104];
  __shared__ __align__(16) unsigned short Wt[96][104];
  __shared__ __align__(16) unsigned short inter[32][392];
  __shared__ float gLds[96], bLds[96];
  __shared__ float pSum[256], pSq[256];
  __shared__ float mLds[32], sLds[32];
  const int tid = threadIdx.x;
  const int wave = tid >> 6, lane = tid & 63;
  const int row0 = blockIdx.x * 32;
  const int ml = lane & 15, q8 = (lane >> 4) * 8;
  const int mt = (wave * 3) / 6;
  const int nt0 = (wave * 3) % 6;

  if (tid < 96) { gLds[tid] = n2g[tid]; bLds[tid] = n2b[tid]; }
  for (int i = tid; i < 384; i += 256) {
    const int r = i / 12, kk = (i % 12) * 8;
    *(uint4*)&As[r][kk] = *(const uint4*)(xresb + (size_t)(row0 + r)*96 + kk);
  }
  __syncthreads();

  {
    const int r = tid & 31, seg = tid >> 5;
    float s = 0.0f, sq = 0.0f;
    #pragma unroll
    for (int j = 0; j < 12; ++j) {
      const float v = bfval(As[r][seg*12 + j]);
      s += v; sq += v*v;
    }
    pSum[tid] = s; pSq[tid] = sq;
  }
  __syncthreads();
  if (tid < 32) {
    float s = 0.0f, sq = 0.0f;
    #pragma unroll
    for (int k = 0; k < 8; ++k) { s += pSum[tid + 32*k]; sq += pSq[tid + 32*k]; }
    const float mean = s * (1.0f/96.0f);
    mLds[tid] = mean;
    sLds[tid] = rsqrtf(sq*(1.0f/96.0f) - mean*mean + 1e-5f);
  }
  __syncthreads();
  for (int i = tid; i < 384; i += 256) {
    const int r = i / 12, kk = (i % 12) * 8;
    uint4 u = *(uint4*)&As[r][kk];
    const float m = mLds[r], sc = sLds[r];
    float v[8];
    v[0]=bflo(u.x); v[1]=bfhi(u.x); v[2]=bflo(u.y); v[3]=bfhi(u.y);
    v[4]=bflo(u.z); v[5]=bfhi(u.z); v[6]=bflo(u.w); v[7]=bfhi(u.w);
    #pragma unroll
    for (int j = 0; j < 8; ++j) v[j] = (v[j] - m)*sc*gLds[kk+j] + bLds[kk+j];
    *(uint4*)&As[r][kk] = pack8(v);
  }

  for (int ny = 0; ny < 4; ++ny) {
    __syncthreads();
    for (int i = tid; i < 1152; i += 256) {
      const int k = i % 96, nn8 = (i / 96) * 8;
      float t[8];
      *(float4*)&t[0] = *(const float4*)(w1 + (size_t)k*384 + ny*96 + nn8);
      *(float4*)&t[4] = *(const float4*)(w1 + (size_t)k*384 + ny*96 + nn8 + 4);
      #pragma unroll
      for (int j = 0; j < 8; ++j) Wt[nn8 + j][k] = f2bfbits(t[j]);
    }
    __syncthreads();

    f32x4 acc[3];
    #pragma unroll
    for (int i = 0; i < 3; ++i) acc[i] = (f32x4){0.f, 0.f, 0.f, 0.f};
    #pragma unroll
    for (int kc = 0; kc < 3; ++kc) {
      const short8 a = *(const short8*)&As[mt*16 + ml][kc*32 + q8];
      #pragma unroll
      for (int i = 0; i < 3; ++i) {
        const short8 b = *(const short8*)&Wt[(nt0 + i)*16 + ml][kc*32 + q8];
        acc[i] = __builtin_amdgcn_mfma_f32_16x16x32_bf16(a, b, acc[i], 0, 0, 0);
      }
    }
    #pragma unroll
    for (int i = 0; i < 3; ++i) {
      #pragma unroll
      for (int r = 0; r < 4; ++r) {
        const int row = mt*16 + (lane >> 4)*4 + r;
        const int col = ny*96 + (nt0 + i)*16 + ml;
        float v = acc[i][r] + b1[col];
        v = 0.5f * v * (1.0f + erff(v * 0.70710678118654752f));
        inter[row][col] = f2bfbits(v);
      }
    }
  }

  f32x4 acc2[3];
  #pragma unroll
  for (int i = 0; i < 3; ++i) acc2[i] = (f32x4){0.f, 0.f, 0.f, 0.f};
  for (int kc4 = 0; kc4 < 4; ++kc4) {
    __syncthreads();
    for (int i = tid; i < 1152; i += 256) {
      const int k = i % 96, nn8 = (i / 96) * 8;
      float t[8];
      *(float4*)&t[0] = *(const float4*)(w2 + (size_t)(kc4*96 + k)*96 + nn8);
      *(float4*)&t[4] = *(const float4*)(w2 + (size_t)(kc4*96 + k)*96 + nn8 + 4);
      #pragma unroll
      for (int j = 0; j < 8; ++j) Wt[nn8 + j][k] = f2bfbits(t[j]);
    }
    __syncthreads();

    #pragma unroll
    for (int kc = 0; kc < 3; ++kc) {
      const short8 a = *(const short8*)&inter[mt*16 + ml][kc4*96 + kc*32 + q8];
      #pragma unroll
      for (int i = 0; i < 3; ++i) {
        const short8 b = *(const short8*)&Wt[(nt0 + i)*16 + ml][kc*32 + q8];
        acc2[i] = __builtin_amdgcn_mfma_f32_16x16x32_bf16(a, b, acc2[i], 0, 0, 0);
      }
    }
  }

  const unsigned short* xu = (const unsigned short*)xresb;
  #pragma unroll
  for (int i = 0; i < 3; ++i) {
    #pragma unroll
    for (int r = 0; r < 4; ++r) {
      const size_t row = (size_t)(row0 + mt*16 + (lane >> 4)*4 + r);
      const int col = (nt0 + i)*16 + ml;
      out[row*96 + col] = acc2[i][r] + b2[col] + bfval(xu[row*96 + col]);
    }
  }
}

// ---------------------------------------------------------------------------
// Launch. ws layout (proven in round 6): qb [0,E) el, kb [E,2E), vb [2E,3E)
// (E = L*96 elements; 6E bytes total). xres overlays ws in phase B; d_out
// doubles as attention-output scratch.
// ---------------------------------------------------------------------------
extern "C" void kernel_launch(void* const* d_in, const int* in_sizes, int n_in,
                              void* d_out, int out_size, void* d_ws, size_t ws_size,
                              hipStream_t stream)
{
  (void)in_sizes; (void)n_in; (void)out_size; (void)ws_size;
  const float* x    = (const float*)d_in[0];
  const float* n1g  = (const float*)d_in[1];
  const float* n1b  = (const float*)d_in[2];
  const float* qkvw = (const float*)d_in[3];
  const float* qkvb = (const float*)d_in[4];
  const float* rpb  = (const float*)d_in[5];
  const float* pw   = (const float*)d_in[6];
  const float* pb   = (const float*)d_in[7];
  const float* n2g  = (const float*)d_in[8];
  const float* n2b  = (const float*)d_in[9];
  const float* f1w  = (const float*)d_in[10];
  const float* f1b  = (const float*)d_in[11];
  const float* f2w  = (const float*)d_in[12];
  const float* f2b  = (const float*)d_in[13];
  float* out = (float*)d_out;

  const size_t E = (size_t)L_TOK * 96;           // elements
  __hip_bfloat16* qb = (__hip_bfloat16*)d_ws;    // E elements (3 heads)
  __hip_bfloat16* kb = qb + E;
  __hip_bfloat16* vb = kb + E;
  __hip_bfloat16* xres = (__hip_bfloat16*)d_ws;  // phase-B overlay
  float* ob = out;                               // d_out as attention scratch
  const size_t hs = (size_t)L_TOK * 32;

  k_qkv_ln<<<dim3(L_TOK/64, 3), 256, 0, stream>>>(
      x, n1g, n1b, qkvw, qkvb, hs, qb, kb, vb);
  k_attn_mfma<<<dim3(256, 3), 128, 0, stream>>>(qb, kb, vb, hs, rpb, ob);
  k_proj<<<L_TOK/64, 256, 0, stream>>>(ob, pw, pb, x, xres);
  k_mlp<<<L_TOK/32, 256, 0, stream>>>(xres, n2g, n2b, f1w, f1b, f2w, f2b, out);
}

// Round 8
// 362.047 us; speedup vs baseline: 3.6980x; 1.1746x over previous
//
#include <hip/hip_runtime.h>
#include <hip/hip_bf16.h>

// ---------------------------------------------------------------------------
// SwinTransformerBlock3D, f32 I/O. Round 8: pre-transposed bf16 weights in
// scratch; GEMM B-fragments read directly from global (L1/L2-hot) — per-block
// Wt LDS staging deleted (round-7 k_mlp: MfmaUtil 2.7%, staging-bound).
//   qkvwt[288][96] -> d_out scratch (clobbered later by attention, by design)
//   pwt[96][96], w1t[384][96], w2t[96][384] -> ws kb/vb region (dead post-attn)
// Attention kernel unchanged (proven). absmax budget unchanged (bf16 internals).
// ---------------------------------------------------------------------------

#define L_TOK 87808

typedef unsigned int uint;
typedef __attribute__((ext_vector_type(8))) short short8;
typedef __attribute__((ext_vector_type(4))) float f32x4;

__device__ __forceinline__ float bflo(uint u){ union{uint x; float f;} a; a.x = u << 16; return a.f; }
__device__ __forceinline__ float bfhi(uint u){ union{uint x; float f;} a; a.x = u & 0xffff0000u; return a.f; }
__device__ __forceinline__ float bfval(unsigned short w){ union{uint x; float f;} a; a.x = (uint)w << 16; return a.f; }
__device__ __forceinline__ unsigned short f2bfbits(float f){
  union{float f; uint u;} a; a.f = f;
  uint u = a.u;
  u += 0x7fffu + ((u >> 16) & 1u);           // round-to-nearest-even
  return (unsigned short)(u >> 16);
}
__device__ __forceinline__ uint pack2(float a, float b){
  return ((uint)f2bfbits(b) << 16) | (uint)f2bfbits(a);
}
__device__ __forceinline__ uint4 pack8(const float* p){
  uint4 u;
  u.x = pack2(p[0], p[1]); u.y = pack2(p[2], p[3]);
  u.z = pack2(p[4], p[5]); u.w = pack2(p[6], p[7]);
  return u;
}
__device__ __forceinline__ uint4 pack8g(const float* gp){
  float t[8];
  *(float4*)&t[0] = *(const float4*)gp;
  *(float4*)&t[4] = *(const float4*)(gp + 4);
  return pack8(t);
}

// ---------------------------------------------------------------------------
// K0: transpose+convert weights: dst[n*K + k] = bf16(src[k*N + n]).
// ---------------------------------------------------------------------------
__global__ __launch_bounds__(256)
void k_tr(const float* __restrict__ src, unsigned short* __restrict__ dst,
          int K, int N)
{
  const int idx = blockIdx.x * 256 + threadIdx.x;
  if (idx < K * N) {
    const int n = idx / K, k = idx % K;
    dst[idx] = f2bfbits(src[(size_t)k * N + n]);
  }
}

// ---------------------------------------------------------------------------
// K1: fused LN1 + shift + window gather + per-head QKV GEMM (MFMA).
// B-frags from qkvwt (global, n-major bf16). No Wt LDS.
// ---------------------------------------------------------------------------
__global__ __launch_bounds__(256)
void k_qkv_ln(const float* __restrict__ x,
              const float* __restrict__ n1g,
              const float* __restrict__ n1b,
              const unsigned short* __restrict__ qkvwt,   // [288][96]
              const float* __restrict__ bias, size_t headStride,
              __hip_bfloat16* __restrict__ qb,
              __hip_bfloat16* __restrict__ kb,
              __hip_bfloat16* __restrict__ vb)
{
  __shared__ __align__(16) unsigned short As[64][104];
  __shared__ uint srcOff[64];
  __shared__ float gLds[96], bLds[96];
  __shared__ float pSum[256], pSq[256];
  __shared__ float mLds[64], sLds[64];

  const int tid = threadIdx.x;
  const int wave = tid >> 6, lane = tid & 63;
  const int row0 = blockIdx.x * 64;
  const int h = (int)blockIdx.y;
  __hip_bfloat16* qh = qb + (size_t)h * headStride;
  __hip_bfloat16* kh = kb + (size_t)h * headStride;
  __hip_bfloat16* vh = vb + (size_t)h * headStride;

  if (tid < 64) {
    const uint row = (uint)(row0 + tid);
    const uint win = row / 343u, n = row % 343u;
    const uint wh = win >> 5, ww = (win >> 2) & 7u, wd = win & 3u;
    const uint ih = n / 49u, rr = n % 49u, iw = rr / 7u, id = rr % 7u;
    uint gh = wh*7u + ih + 3u; if (gh >= 56u) gh -= 56u;
    uint gw = ww*7u + iw + 3u; if (gw >= 56u) gw -= 56u;
    uint gd = wd*7u + id + 3u; if (gd >= 28u) gd -= 28u;
    srcOff[tid] = ((gh*56u + gw)*28u + gd) * 96u;
  }
  if (tid < 96) { gLds[tid] = n1g[tid]; bLds[tid] = n1b[tid]; }
  __syncthreads();

  for (int i = tid; i < 768; i += 256) {
    const int r = i / 12, kk = (i % 12) * 8;
    *(uint4*)&As[r][kk] = pack8g(x + srcOff[r] + kk);
  }
  __syncthreads();

  {
    const int r = tid & 63, seg = tid >> 6;
    float s = 0.0f, sq = 0.0f;
    #pragma unroll
    for (int j = 0; j < 24; ++j) {
      const float v = bfval(As[r][seg*24 + j]);
      s += v; sq += v*v;
    }
    pSum[tid] = s; pSq[tid] = sq;
  }
  __syncthreads();
  if (tid < 64) {
    const float s  = pSum[tid] + pSum[tid+64] + pSum[tid+128] + pSum[tid+192];
    const float sq = pSq[tid] + pSq[tid+64] + pSq[tid+128] + pSq[tid+192];
    const float mean = s * (1.0f/96.0f);
    mLds[tid] = mean;
    sLds[tid] = rsqrtf(sq*(1.0f/96.0f) - mean*mean + 1e-5f);
  }
  __syncthreads();
  for (int i = tid; i < 768; i += 256) {
    const int r = i / 12, kk = (i % 12) * 8;
    uint4 u = *(uint4*)&As[r][kk];
    const float m = mLds[r], sc = sLds[r];
    float v[8];
    v[0]=bflo(u.x); v[1]=bfhi(u.x); v[2]=bflo(u.y); v[3]=bfhi(u.y);
    v[4]=bflo(u.z); v[5]=bfhi(u.z); v[6]=bflo(u.w); v[7]=bfhi(u.w);
    #pragma unroll
    for (int j = 0; j < 8; ++j) v[j] = (v[j] - m)*sc*gLds[kk+j] + bLds[kk+j];
    *(uint4*)&As[r][kk] = pack8(v);
  }
  __syncthreads();

  f32x4 acc[6];
  #pragma unroll
  for (int i = 0; i < 6; ++i) acc[i] = (f32x4){0.f, 0.f, 0.f, 0.f};
  const int ml = lane & 15, q8 = (lane >> 4) * 8;
  #pragma unroll
  for (int nt = 0; nt < 6; ++nt) {
    const int col = nt*16 + ml;
    const int wcol = (col >> 5)*96 + h*32 + (col & 31);
    #pragma unroll
    for (int kc = 0; kc < 3; ++kc) {
      const short8 a = *(const short8*)&As[wave*16 + ml][kc*32 + q8];
      const short8 b = *(const short8*)(qkvwt + (size_t)wcol*96 + kc*32 + q8);
      acc[nt] = __builtin_amdgcn_mfma_f32_16x16x32_bf16(a, b, acc[nt], 0, 0, 0);
    }
  }

  const float qscale = 0.17677669529663687f;   // 32^-0.5
  #pragma unroll
  for (int r = 0; r < 4; ++r) {
    const size_t row = (size_t)(row0 + wave*16 + (lane >> 4)*4 + r);
    #pragma unroll
    for (int nt = 0; nt < 6; ++nt) {
      const int col = nt*16 + ml;
      const int part = col >> 5, d = col & 31;
      float v = acc[nt][r] + bias[part*96 + h*32 + d];
      if (part == 0) v *= qscale;
      __hip_bfloat16* dst = (part == 0) ? qh : ((part == 1) ? kh : vh);
      dst[row*32 + d] = __float2bfloat16(v);
    }
  }
}

// ---------------------------------------------------------------------------
// K2: MFMA attention (unchanged from round 7, proven).
// ---------------------------------------------------------------------------
__global__ __launch_bounds__(128)
void k_attn_mfma(const __hip_bfloat16* __restrict__ qg,
                 const __hip_bfloat16* __restrict__ kg,
                 const __hip_bfloat16* __restrict__ vg,
                 size_t headStride,
                 const float* __restrict__ rpbg,
                 float* __restrict__ ob)
{
  __shared__ __align__(16) unsigned short vt[32*344 + 16];
  __shared__ __align__(16) unsigned short Pbuf[2][16*352];
  __shared__ unsigned short rpB[2197];
  __shared__ short baseT[352];
  __shared__ unsigned char cntT[352];

  const int tid = threadIdx.x;
  const int wave = tid >> 6, lane = tid & 63;
  const uint win = blockIdx.x;
  const int hh = (int)blockIdx.y;
  const size_t wbase = (size_t)hh * headStride + (size_t)win * (343*32);
  const unsigned short* qw = (const unsigned short*)qg + wbase;
  const unsigned short* kw = (const unsigned short*)kg + wbase;
  const unsigned short* vw = (const unsigned short*)vg + wbase;

  for (int i = tid; i < 2197; i += 128) rpB[i] = f2bfbits(rpbg[i*3 + hh]);
  const uint wh = win >> 5, ww = (win >> 2) & 7u, wd = win & 3u;
  for (int i = tid; i < 352; i += 128) {
    if (i < 343) {
      const uint c0 = (uint)i/49u, rr = (uint)i%49u, c1 = rr/7u, c2 = rr%7u;
      baseT[i] = (short)(c0*169u + c1*13u + c2);
      const uint g0 = wh*7u + c0, g1 = ww*7u + c1, g2 = wd*7u + c2;
      const uint rh = (g0 < 49u) ? 0u : ((g0 < 53u) ? 1u : 2u);
      const uint rw = (g1 < 49u) ? 0u : ((g1 < 53u) ? 1u : 2u);
      const uint rd = (g2 < 21u) ? 0u : ((g2 < 25u) ? 1u : 2u);
      cntT[i] = (unsigned char)(rh*9u + rw*3u + rd);
    } else { baseT[i] = 0; cntT[i] = 255; }
  }
  for (int t = tid; t < 343; t += 128) {
    const uint4* src = (const uint4*)(vw + (size_t)t*32);
    #pragma unroll
    for (int c4 = 0; c4 < 4; ++c4) {
      const uint4 u = src[c4];
      const int d = c4*8;
      vt[(d+0)*344 + t] = (unsigned short)(u.x & 0xffffu);
      vt[(d+1)*344 + t] = (unsigned short)(u.x >> 16);
      vt[(d+2)*344 + t] = (unsigned short)(u.y & 0xffffu);
      vt[(d+3)*344 + t] = (unsigned short)(u.y >> 16);
      vt[(d+4)*344 + t] = (unsigned short)(u.z & 0xffffu);
      vt[(d+5)*344 + t] = (unsigned short)(u.z >> 16);
      vt[(d+6)*344 + t] = (unsigned short)(u.w & 0xffffu);
      vt[(d+7)*344 + t] = (unsigned short)(u.w >> 16);
    }
  }
  if (tid < 32) vt[tid*344 + 343] = 0;
  if (tid < 16) vt[32*344 + tid] = 0;
  __syncthreads();

  const int ml = lane & 15, g8 = (lane >> 4) * 8;
  unsigned short* Pw = &Pbuf[wave][0];

  for (int mt = wave; mt < 22; mt += 2) {
    const short8 qf = *(const short8*)(qw + (size_t)(mt*16 + ml)*32 + g8);
    f32x4 s[22];
    #pragma unroll
    for (int nt = 0; nt < 22; ++nt) {
      const short8 kf = *(const short8*)(kw + (size_t)(nt*16 + ml)*32 + g8);
      s[nt] = __builtin_amdgcn_mfma_f32_16x16x32_bf16(qf, kf, (f32x4){0.f,0.f,0.f,0.f}, 0, 0, 0);
    }

    int biR[4], cnR[4];
    #pragma unroll
    for (int r = 0; r < 4; ++r) {
      const int gi = mt*16 + (lane >> 4)*4 + r;
      biR[r] = (int)baseT[gi] + 1098;
      cnR[r] = (int)cntT[gi];
    }

    float mx[4] = {-1e30f, -1e30f, -1e30f, -1e30f};
    #pragma unroll
    for (int nt = 0; nt < 22; ++nt) {
      const int col = nt*16 + ml;
      const int bj = (int)baseT[col];
      const int cj = (int)cntT[col];
      #pragma unroll
      for (int r = 0; r < 4; ++r) {
        float v = s[nt][r] + bfval(rpB[biR[r] - bj]);
        v += (cj == cnR[r]) ? 0.0f : -100.0f;
        v = (col < 343) ? v : -1e30f;
        s[nt][r] = v;
        mx[r] = fmaxf(mx[r], v);
      }
    }
    float sm[4];
    #pragma unroll
    for (int r = 0; r < 4; ++r) {
      float m = mx[r];
      m = fmaxf(m, __shfl_xor(m, 1));
      m = fmaxf(m, __shfl_xor(m, 2));
      m = fmaxf(m, __shfl_xor(m, 4));
      m = fmaxf(m, __shfl_xor(m, 8));
      mx[r] = m; sm[r] = 0.0f;
    }
    #pragma unroll
    for (int nt = 0; nt < 22; ++nt) {
      #pragma unroll
      for (int r = 0; r < 4; ++r) {
        const float p = __expf(s[nt][r] - mx[r]);
        s[nt][r] = p;
        sm[r] += p;
      }
    }
    #pragma unroll
    for (int r = 0; r < 4; ++r) {
      float t = sm[r];
      t += __shfl_xor(t, 1);
      t += __shfl_xor(t, 2);
      t += __shfl_xor(t, 4);
      t += __shfl_xor(t, 8);
      sm[r] = t;
    }
    #pragma unroll
    for (int nt = 0; nt < 22; ++nt) {
      #pragma unroll
      for (int r = 0; r < 4; ++r)
        Pw[((lane >> 4)*4 + r)*352 + nt*16 + ml] = f2bfbits(s[nt][r]);
    }
    f32x4 o0 = {0.f,0.f,0.f,0.f}, o1 = {0.f,0.f,0.f,0.f};
    #pragma unroll
    for (int kc = 0; kc < 11; ++kc) {
      const short8 pf = *(const short8*)&Pw[ml*352 + kc*32 + g8];
      const short8 b0 = *(const short8*)&vt[(size_t)ml*344 + kc*32 + g8];
      const short8 b1 = *(const short8*)&vt[(size_t)(16 + ml)*344 + kc*32 + g8];
      o0 = __builtin_amdgcn_mfma_f32_16x16x32_bf16(pf, b0, o0, 0, 0, 0);
      o1 = __builtin_amdgcn_mfma_f32_16x16x32_bf16(pf, b1, o1, 0, 0, 0);
    }
    #pragma unroll
    for (int r = 0; r < 4; ++r) {
      const int row = mt*16 + (lane >> 4)*4 + r;
      if (row < 343) {
        const float inv = 1.0f / sm[r];
        float* op = ob + ((size_t)win*343 + (uint)row)*96 + hh*32;
        op[ml]      = o0[r] * inv;
        op[16 + ml] = o1[r] * inv;
      }
    }
  }
}

// ---------------------------------------------------------------------------
// K3: proj + window reverse + roll(+3) + residual -> xres bf16 (MFMA).
// B-frags from pwt (global). No Wt LDS.
// ---------------------------------------------------------------------------
__global__ __launch_bounds__(256)
void k_proj(const float* __restrict__ A,
            const unsigned short* __restrict__ pwt,      // [96][96]
            const float* __restrict__ bias,
            const float* __restrict__ xin,
            __hip_bfloat16* __restrict__ xres)
{
  __shared__ __align__(16) unsigned short As[64][104];
  const int tid = threadIdx.x;
  const int wave = tid >> 6, lane = tid & 63;
  const int row0 = blockIdx.x * 64;

  for (int i = tid; i < 768; i += 256) {
    const int r = i / 12, kk = (i % 12) * 8;
    *(uint4*)&As[r][kk] = pack8g(A + (size_t)(row0 + r)*96 + kk);
  }
  __syncthreads();

  f32x4 acc[6];
  #pragma unroll
  for (int i = 0; i < 6; ++i) acc[i] = (f32x4){0.f, 0.f, 0.f, 0.f};
  const int ml = lane & 15, q8 = (lane >> 4) * 8;
  #pragma unroll
  for (int kc = 0; kc < 3; ++kc) {
    const short8 a = *(const short8*)&As[wave*16 + ml][kc*32 + q8];
    #pragma unroll
    for (int nt = 0; nt < 6; ++nt) {
      const short8 b = *(const short8*)(pwt + (size_t)(nt*16 + ml)*96 + kc*32 + q8);
      acc[nt] = __builtin_amdgcn_mfma_f32_16x16x32_bf16(a, b, acc[nt], 0, 0, 0);
    }
  }

  #pragma unroll
  for (int r = 0; r < 4; ++r) {
    const uint row = (uint)(row0 + wave*16 + (lane >> 4)*4 + r);
    const uint win = row / 343u, n = row % 343u;
    const uint wh = win >> 5, ww = (win >> 2) & 7u, wd = win & 3u;
    const uint ih = n / 49u, rr = n % 49u, iw = rr / 7u, id = rr % 7u;
    uint gh = wh*7u + ih + 3u; if (gh >= 56u) gh -= 56u;
    uint gw = ww*7u + iw + 3u; if (gw >= 56u) gw -= 56u;
    uint gd = wd*7u + id + 3u; if (gd >= 28u) gd -= 28u;
    const size_t gt = (size_t)((gh*56u + gw)*28u + gd) * 96;
    #pragma unroll
    for (int nt = 0; nt < 6; ++nt) {
      const int col = nt*16 + ml;
      xres[gt + col] = __float2bfloat16(acc[nt][r] + bias[col] + xin[gt + col]);
    }
  }
}

// ---------------------------------------------------------------------------
// K4: fused LN2 + MLP (MFMA). B-frags from w1t/w2t (global). Only As + inter
// in LDS; 5 barriers total.
// ---------------------------------------------------------------------------
__global__ __launch_bounds__(256)
void k_mlp(const __hip_bfloat16* __restrict__ xresb,
           const float* __restrict__ n2g,
           const float* __restrict__ n2b,
           const unsigned short* __restrict__ w1t,       // [384][96]
           const float* __restrict__ b1,
           const unsigned short* __restrict__ w2t,       // [96][384]
           const float* __restrict__ b2,
           float* __restrict__ out)
{
  __shared__ __align__(16) unsigned short As[32][104];
  __shared__ __align__(16) unsigned short inter[32][392];
  __shared__ float gLds[96], bLds[96];
  __shared__ float pSum[256], pSq[256];
  __shared__ float mLds[32], sLds[32];
  const int tid = threadIdx.x;
  const int wave = tid >> 6, lane = tid & 63;
  const int row0 = blockIdx.x * 32;
  const int ml = lane & 15, q8 = (lane >> 4) * 8;
  const int mt = (wave * 3) / 6;
  const int nt0 = (wave * 3) % 6;

  if (tid < 96) { gLds[tid] = n2g[tid]; bLds[tid] = n2b[tid]; }
  for (int i = tid; i < 384; i += 256) {
    const int r = i / 12, kk = (i % 12) * 8;
    *(uint4*)&As[r][kk] = *(const uint4*)(xresb + (size_t)(row0 + r)*96 + kk);
  }
  __syncthreads();

  {
    const int r = tid & 31, seg = tid >> 5;
    float s = 0.0f, sq = 0.0f;
    #pragma unroll
    for (int j = 0; j < 12; ++j) {
      const float v = bfval(As[r][seg*12 + j]);
      s += v; sq += v*v;
    }
    pSum[tid] = s; pSq[tid] = sq;
  }
  __syncthreads();
  if (tid < 32) {
    float s = 0.0f, sq = 0.0f;
    #pragma unroll
    for (int k = 0; k < 8; ++k) { s += pSum[tid + 32*k]; sq += pSq[tid + 32*k]; }
    const float mean = s * (1.0f/96.0f);
    mLds[tid] = mean;
    sLds[tid] = rsqrtf(sq*(1.0f/96.0f) - mean*mean + 1e-5f);
  }
  __syncthreads();
  for (int i = tid; i < 384; i += 256) {
    const int r = i / 12, kk = (i % 12) * 8;
    uint4 u = *(uint4*)&As[r][kk];
    const float m = mLds[r], sc = sLds[r];
    float v[8];
    v[0]=bflo(u.x); v[1]=bfhi(u.x); v[2]=bflo(u.y); v[3]=bfhi(u.y);
    v[4]=bflo(u.z); v[5]=bfhi(u.z); v[6]=bflo(u.w); v[7]=bfhi(u.w);
    #pragma unroll
    for (int j = 0; j < 8; ++j) v[j] = (v[j] - m)*sc*gLds[kk+j] + bLds[kk+j];
    *(uint4*)&As[r][kk] = pack8(v);
  }
  __syncthreads();

  // ---- fc1 + GELU -> inter ----
  for (int ny = 0; ny < 4; ++ny) {
    f32x4 acc[3];
    #pragma unroll
    for (int i = 0; i < 3; ++i) acc[i] = (f32x4){0.f, 0.f, 0.f, 0.f};
    #pragma unroll
    for (int kc = 0; kc < 3; ++kc) {
      const short8 a = *(const short8*)&As[mt*16 + ml][kc*32 + q8];
      #pragma unroll
      for (int i = 0; i < 3; ++i) {
        const int n = ny*96 + (nt0 + i)*16 + ml;
        const short8 b = *(const short8*)(w1t + (size_t)n*96 + kc*32 + q8);
        acc[i] = __builtin_amdgcn_mfma_f32_16x16x32_bf16(a, b, acc[i], 0, 0, 0);
      }
    }
    #pragma unroll
    for (int i = 0; i < 3; ++i) {
      #pragma unroll
      for (int r = 0; r < 4; ++r) {
        const int row = mt*16 + (lane >> 4)*4 + r;
        const int col = ny*96 + (nt0 + i)*16 + ml;
        float v = acc[i][r] + b1[col];
        v = 0.5f * v * (1.0f + erff(v * 0.70710678118654752f));
        inter[row][col] = f2bfbits(v);
      }
    }
  }
  __syncthreads();

  // ---- fc2 ----
  f32x4 acc2[3];
  #pragma unroll
  for (int i = 0; i < 3; ++i) acc2[i] = (f32x4){0.f, 0.f, 0.f, 0.f};
  for (int kc = 0; kc < 12; ++kc) {
    const short8 a = *(const short8*)&inter[mt*16 + ml][kc*32 + q8];
    #pragma unroll
    for (int i = 0; i < 3; ++i) {
      const int n = (nt0 + i)*16 + ml;
      const short8 b = *(const short8*)(w2t + (size_t)n*384 + kc*32 + q8);
      acc2[i] = __builtin_amdgcn_mfma_f32_16x16x32_bf16(a, b, acc2[i], 0, 0, 0);
    }
  }

  const unsigned short* xu = (const unsigned short*)xresb;
  #pragma unroll
  for (int i = 0; i < 3; ++i) {
    #pragma unroll
    for (int r = 0; r < 4; ++r) {
      const size_t row = (size_t)(row0 + mt*16 + (lane >> 4)*4 + r);
      const int col = (nt0 + i)*16 + ml;
      out[row*96 + col] = acc2[i][r] + b2[col] + bfval(xu[row*96 + col]);
    }
  }
}

// ---------------------------------------------------------------------------
// Launch. ws bytes: qb [0,2E), kb [2E,4E), vb [4E,6E)  (E = L*96 elements).
// qkvwt lives in d_out (scratch; attention clobbers it afterwards — by design).
// pwt/w1t/w2t live in the dead kb region after attention. xres overlays qb.
// ---------------------------------------------------------------------------
extern "C" void kernel_launch(void* const* d_in, const int* in_sizes, int n_in,
                              void* d_out, int out_size, void* d_ws, size_t ws_size,
                              hipStream_t stream)
{
  (void)in_sizes; (void)n_in; (void)out_size; (void)ws_size;
  const float* x    = (const float*)d_in[0];
  const float* n1g  = (const float*)d_in[1];
  const float* n1b  = (const float*)d_in[2];
  const float* qkvw = (const float*)d_in[3];
  const float* qkvb = (const float*)d_in[4];
  const float* rpb  = (const float*)d_in[5];
  const float* pw   = (const float*)d_in[6];
  const float* pb   = (const float*)d_in[7];
  const float* n2g  = (const float*)d_in[8];
  const float* n2b  = (const float*)d_in[9];
  const float* f1w  = (const float*)d_in[10];
  const float* f1b  = (const float*)d_in[11];
  const float* f2w  = (const float*)d_in[12];
  const float* f2b  = (const float*)d_in[13];
  float* out = (float*)d_out;

  const size_t E = (size_t)L_TOK * 96;           // elements
  __hip_bfloat16* qb = (__hip_bfloat16*)d_ws;
  __hip_bfloat16* kb = qb + E;
  __hip_bfloat16* vb = kb + E;
  __hip_bfloat16* xres = (__hip_bfloat16*)d_ws;  // overlays qb in phase B
  float* ob = out;
  const size_t hs = (size_t)L_TOK * 32;

  unsigned short* qkvwt = (unsigned short*)d_out;       // 27648 el, pre-attn only
  unsigned short* pwt   = (unsigned short*)kb;          // dead kb region post-attn
  unsigned short* w1t   = pwt + 9216;
  unsigned short* w2t   = w1t + 36864;

  k_tr<<<108, 256, 0, stream>>>(qkvw, qkvwt, 96, 288);
  k_qkv_ln<<<dim3(L_TOK/64, 3), 256, 0, stream>>>(
      x, n1g, n1b, qkvwt, qkvb, hs, qb, kb, vb);
  k_attn_mfma<<<dim3(256, 3), 128, 0, stream>>>(qb, kb, vb, hs, rpb, ob);
  k_tr<<<36, 256, 0, stream>>>(pw, pwt, 96, 96);
  k_tr<<<144, 256, 0, stream>>>(f1w, w1t, 96, 384);
  k_tr<<<144, 256, 0, stream>>>(f2w, w2t, 384, 96);
  k_proj<<<L_TOK/64, 256, 0, stream>>>(ob, pwt, pb, x, xres);
  k_mlp<<<L_TOK/32, 256, 0, stream>>>(xres, n2g, n2b, w1t, f1b, w2t, f2b, out);
}